// Round 3
// baseline (430.910 us; speedup 1.0000x reference)
//
#include <hip/hip_runtime.h>

#define HID 64
#define DIN 128
#define KBLK 1024               // edge-count blocks
#define SBLK 1024               // scatter blocks

typedef unsigned long long ull;
typedef unsigned short u16;

static __device__ __forceinline__ u16 f2bf(float f) {
  unsigned u = __float_as_uint(f);
  unsigned lsb = (u >> 16) & 1u;
  u += 0x7fffu + lsb;
  return (u16)(u >> 16);
}

// ============ K1: per-node edge counts + weighted degree + bucket sums ============
// Counters (cnt[N], deg[N], bsum[256]) are L2-resident (~400 KB); avg 32 hits per
// node counter -> negligible contention. LDS-aggregated bucket histogram keeps the
// hot 196-entry bsum array off the per-edge atomic path.
// Trailing blocks (b >= KBLK) do the weight transposes (fused launch).

__global__ __launch_bounds__(512) void k_cnt(const int* __restrict__ dst,
                                             const float* __restrict__ ew,
                                             int* __restrict__ cnt,
                                             float* __restrict__ deg,
                                             int* __restrict__ bsum,
                                             int E,
                                             const float* __restrict__ W1,
                                             const float* __restrict__ W2,
                                             float* __restrict__ WT1,
                                             float* __restrict__ WT2) {
  int b = blockIdx.x, tid = threadIdx.x;
  if (b >= KBLK) {               // weight-transpose tail blocks
    int idx = (b - KBLK) * 512 + tid;
    if (idx < DIN * 64) {
      int d = idx >> 6, j = idx & 63;
      WT1[idx] = W1[j * DIN + d];
    }
    int i2 = idx - DIN * 64;
    if (i2 >= 0 && i2 < HID * 64) {
      int d = i2 >> 6, j = i2 & 63;
      WT2[i2] = W2[j * HID + d];
    }
    return;
  }
  __shared__ int hb[256];
  if (tid < 256) hb[tid] = 0;
  __syncthreads();
  for (int e = b * 512 + tid; e < E; e += KBLK * 512) {
    int d = dst[e];
    float w = ew[e];
    atomicAdd(&cnt[d], 1);
    atomicAdd(&deg[d], w);
    atomicAdd(&hb[d >> 8], 1);
  }
  __syncthreads();
  if (tid < 256 && hb[tid] > 0) atomicAdd(&bsum[tid], hb[tid]);
}

// ============ K2: per-bucket scan -> gapless CSR offsets + dinv ============
// Block `bin` owns nodes [bin*256, bin*256+256). Bucket base = sum of bsum[0..bin)
// (<=196 L2-hot reads). 256-wide LDS Hillis-Steele gives in-bucket exclusive
// prefix. Also materializes cur[] (scatter cursors) and dinv = rsqrt(1+deg).

__global__ __launch_bounds__(256) void k_scan(const int* __restrict__ cnt,
                                              const float* __restrict__ deg,
                                              const int* __restrict__ bsum,
                                              int* __restrict__ offs,
                                              int* __restrict__ cur,
                                              float* __restrict__ dinv, int N) {
  int bin = blockIdx.x, tid = threadIdx.x;
  __shared__ int sc[256];
  int base = 0;
  for (int j = 0; j < bin; ++j) base += bsum[j];
  int nd = (bin << 8) + tid;
  int own = (nd < N) ? cnt[nd] : 0;
  sc[tid] = own;
  __syncthreads();
  for (int o = 1; o < 256; o <<= 1) {
    int u = (tid >= o) ? sc[tid - o] : 0;
    __syncthreads();
    sc[tid] += u;
    __syncthreads();
  }
  if (nd < N) {
    int excl = sc[tid] - own;
    offs[nd] = base + excl;
    cur[nd]  = base + excl;
    dinv[nd] = rsqrtf(1.0f + deg[nd]);   // self-loop w=1; deg>=1
  }
}

// ============ K3: direct scatter to final CSR position, norm inline ============
// p = atomicAdd(cur[dst]) -> bufB[p] = (norm, src). Writes are random 8B but the
// 12.8 MB target is L2-resident per XCD; dinv gathers hit the 200 KB L2-hot array.

__global__ __launch_bounds__(512) void k_scat(const int* __restrict__ src,
                                              const int* __restrict__ dst,
                                              const float* __restrict__ ew,
                                              const float* __restrict__ dinv,
                                              int* __restrict__ cur,
                                              int2* __restrict__ bufB, int E) {
  for (int e = blockIdx.x * 512 + threadIdx.x; e < E; e += SBLK * 512) {
    int s = src[e], d = dst[e];
    float nrm = dinv[s] * ew[e] * dinv[d];
    int p = atomicAdd(&cur[d], 1);
    bufB[p] = make_int2(__float_as_int(nrm), s);
  }
}

// ============ K4: GEMM: out[N][64] = X[N][K] @ W[64][K]^T, bf16 output ============
// W pre-transposed (WTg[d][j]); conflict-free float4 LDS staging; inner loop
// 4-wide in d: 8 b128 LDS reads per 64 FMAs -> VALU-bound. (64x64/4x4 measured
// better than 128x64/8x4: 225.4 vs 230.8 us, round-2 data.)

template <int K>
__global__ __launch_bounds__(256) void k_gemm(const float* __restrict__ X,
                                              const float* __restrict__ WTg,
                                              u16* __restrict__ out, int n_nodes) {
  constexpr int PAD = 68;                 // float4-aligned row stride
  __shared__ float XT[64 * PAD];          // XT[m][d]  (row-major)
  __shared__ float WL[64 * PAD];          // WL[d][j]
  const int tid = threadIdx.x;
  const int n0 = blockIdx.x * 64;
  const int tx = tid & 15;                // feature group: j = 4*tx + ji
  const int ty = tid >> 4;                // node group:    m = 4*ty + mi
  float acc[4][4] = {{0.f}};

  for (int ph = 0; ph < K / 64; ++ph) {
    const int d0 = ph * 64;
    __syncthreads();
#pragma unroll
    for (int k = 0; k < 4; ++k) {
      int f = tid + k * 256;              // 0..1023 float4 slots per tile
      int r = f >> 4, q = f & 15;         // r = row, q = float4 column
      int n = n0 + r;
      float4 xv = (n < n_nodes)
        ? *reinterpret_cast<const float4*>(&X[(size_t)n * K + d0 + 4 * q])
        : make_float4(0.f, 0.f, 0.f, 0.f);
      *reinterpret_cast<float4*>(&XT[r * PAD + 4 * q]) = xv;
      float4 wv = *reinterpret_cast<const float4*>(&WTg[(size_t)(d0 + r) * 64 + 4 * q]);
      *reinterpret_cast<float4*>(&WL[r * PAD + 4 * q]) = wv;
    }
    __syncthreads();
#pragma unroll 4
    for (int dd = 0; dd < 64; dd += 4) {
      float4 xs[4], ws[4];
#pragma unroll
      for (int mi = 0; mi < 4; ++mi)
        xs[mi] = *reinterpret_cast<const float4*>(&XT[(4 * ty + mi) * PAD + dd]);
#pragma unroll
      for (int dk = 0; dk < 4; ++dk)
        ws[dk] = *reinterpret_cast<const float4*>(&WL[(dd + dk) * PAD + 4 * tx]);
#pragma unroll
      for (int mi = 0; mi < 4; ++mi) {
        float xm[4] = {xs[mi].x, xs[mi].y, xs[mi].z, xs[mi].w};
#pragma unroll
        for (int dk = 0; dk < 4; ++dk) {
          acc[mi][0] = fmaf(xm[dk], ws[dk].x, acc[mi][0]);
          acc[mi][1] = fmaf(xm[dk], ws[dk].y, acc[mi][1]);
          acc[mi][2] = fmaf(xm[dk], ws[dk].z, acc[mi][2]);
          acc[mi][3] = fmaf(xm[dk], ws[dk].w, acc[mi][3]);
        }
      }
    }
  }

#pragma unroll
  for (int mi = 0; mi < 4; ++mi) {
    int n = n0 + 4 * ty + mi;
    if (n < n_nodes) {
      ushort4 o = make_ushort4(f2bf(acc[mi][0]), f2bf(acc[mi][1]),
                               f2bf(acc[mi][2]), f2bf(acc[mi][3]));
      *reinterpret_cast<ushort4*>(&out[(size_t)n * HID + 4 * tx]) = o;
    }
  }
}

// ============ K5: aggregation v6 — eighth-wave per node ============
// Wave = 8 independent 8-lane groups; group g owns one node fully: 8 lanes x
// 8 feats via one 16B (uint4 = 8x bf16) load -> 8 edges per wave-instruction.
// Unroll-8 main loop: 8 gathers in flight per group (64 lines/wave).
// mode 0: out = relu(agg + bias)          (layer 1 -> h1, fp32)
// mode 1: out = agg + bias + resid        (layer 2 -> final, fp32)

__device__ __forceinline__ void bfma8(const uint4& v, float w, float* a) {
  a[0] = fmaf(__uint_as_float(v.x << 16), w, a[0]);
  a[1] = fmaf(__uint_as_float(v.x & 0xffff0000u), w, a[1]);
  a[2] = fmaf(__uint_as_float(v.y << 16), w, a[2]);
  a[3] = fmaf(__uint_as_float(v.y & 0xffff0000u), w, a[3]);
  a[4] = fmaf(__uint_as_float(v.z << 16), w, a[4]);
  a[5] = fmaf(__uint_as_float(v.z & 0xffff0000u), w, a[5]);
  a[6] = fmaf(__uint_as_float(v.w << 16), w, a[6]);
  a[7] = fmaf(__uint_as_float(v.w & 0xffff0000u), w, a[7]);
}

__global__ __launch_bounds__(256) void k_agg(const u16* __restrict__ h,
                                             const int2* __restrict__ recs,
                                             const int* __restrict__ offs,
                                             const int* __restrict__ cnt,
                                             const float* __restrict__ dinv,
                                             const float* __restrict__ bias,
                                             const float* __restrict__ resid,
                                             float* __restrict__ out, int n_nodes, int mode) {
  int tid = threadIdx.x;
  int lane = tid & 63;
  int g = lane >> 3;                  // group 0..7
  int p8 = (lane & 7) * 8;            // feature base (8 feats per lane)
  int node = (blockIdx.x * 4 + (tid >> 6)) * 8 + g;   // 32 nodes per block
  if (node >= n_nodes) return;
  int beg = offs[node], end = beg + cnt[node];
  float di = dinv[node];

  float a[8], b[8];
  {
    uint4 v = *reinterpret_cast<const uint4*>(&h[(size_t)node * HID + p8]);
    float w = di * di;                // self loop (weight 1.0)
    a[0] = __uint_as_float(v.x << 16) * w;
    a[1] = __uint_as_float(v.x & 0xffff0000u) * w;
    a[2] = __uint_as_float(v.y << 16) * w;
    a[3] = __uint_as_float(v.y & 0xffff0000u) * w;
    a[4] = __uint_as_float(v.z << 16) * w;
    a[5] = __uint_as_float(v.z & 0xffff0000u) * w;
    a[6] = __uint_as_float(v.w << 16) * w;
    a[7] = __uint_as_float(v.w & 0xffff0000u) * w;
#pragma unroll
    for (int j = 0; j < 8; ++j) b[j] = 0.f;
  }

  int i = beg;
  while (i + 8 <= end) {              // 8 gathers in flight per group
    int2 r0 = recs[i];     int2 r1 = recs[i + 1];
    int2 r2 = recs[i + 2]; int2 r3 = recs[i + 3];
    int2 r4 = recs[i + 4]; int2 r5 = recs[i + 5];
    int2 r6 = recs[i + 6]; int2 r7 = recs[i + 7];
    uint4 v0 = *reinterpret_cast<const uint4*>(&h[(size_t)r0.y * HID + p8]);
    uint4 v1 = *reinterpret_cast<const uint4*>(&h[(size_t)r1.y * HID + p8]);
    uint4 v2 = *reinterpret_cast<const uint4*>(&h[(size_t)r2.y * HID + p8]);
    uint4 v3 = *reinterpret_cast<const uint4*>(&h[(size_t)r3.y * HID + p8]);
    uint4 v4 = *reinterpret_cast<const uint4*>(&h[(size_t)r4.y * HID + p8]);
    uint4 v5 = *reinterpret_cast<const uint4*>(&h[(size_t)r5.y * HID + p8]);
    uint4 v6 = *reinterpret_cast<const uint4*>(&h[(size_t)r6.y * HID + p8]);
    uint4 v7 = *reinterpret_cast<const uint4*>(&h[(size_t)r7.y * HID + p8]);
    bfma8(v0, __int_as_float(r0.x), a);
    bfma8(v1, __int_as_float(r1.x), b);
    bfma8(v2, __int_as_float(r2.x), a);
    bfma8(v3, __int_as_float(r3.x), b);
    bfma8(v4, __int_as_float(r4.x), a);
    bfma8(v5, __int_as_float(r5.x), b);
    bfma8(v6, __int_as_float(r6.x), a);
    bfma8(v7, __int_as_float(r7.x), b);
    i += 8;
  }
  if (i + 4 <= end) {
    int2 r0 = recs[i];     int2 r1 = recs[i + 1];
    int2 r2 = recs[i + 2]; int2 r3 = recs[i + 3];
    uint4 v0 = *reinterpret_cast<const uint4*>(&h[(size_t)r0.y * HID + p8]);
    uint4 v1 = *reinterpret_cast<const uint4*>(&h[(size_t)r1.y * HID + p8]);
    uint4 v2 = *reinterpret_cast<const uint4*>(&h[(size_t)r2.y * HID + p8]);
    uint4 v3 = *reinterpret_cast<const uint4*>(&h[(size_t)r3.y * HID + p8]);
    bfma8(v0, __int_as_float(r0.x), a);
    bfma8(v1, __int_as_float(r1.x), b);
    bfma8(v2, __int_as_float(r2.x), a);
    bfma8(v3, __int_as_float(r3.x), b);
    i += 4;
  }
  if (i + 2 <= end) {
    int2 r0 = recs[i];     int2 r1 = recs[i + 1];
    uint4 v0 = *reinterpret_cast<const uint4*>(&h[(size_t)r0.y * HID + p8]);
    uint4 v1 = *reinterpret_cast<const uint4*>(&h[(size_t)r1.y * HID + p8]);
    bfma8(v0, __int_as_float(r0.x), a);
    bfma8(v1, __int_as_float(r1.x), b);
    i += 2;
  }
  if (i < end) {
    int2 r0 = recs[i];
    uint4 v0 = *reinterpret_cast<const uint4*>(&h[(size_t)r0.y * HID + p8]);
    bfma8(v0, __int_as_float(r0.x), a);
  }

  float r[8];
#pragma unroll
  for (int j = 0; j < 8; ++j) r[j] = a[j] + b[j];
  float4 bb0 = *reinterpret_cast<const float4*>(&bias[p8]);
  float4 bb1 = *reinterpret_cast<const float4*>(&bias[p8 + 4]);
  r[0] += bb0.x; r[1] += bb0.y; r[2] += bb0.z; r[3] += bb0.w;
  r[4] += bb1.x; r[5] += bb1.y; r[6] += bb1.z; r[7] += bb1.w;
  if (mode == 0) {
#pragma unroll
    for (int j = 0; j < 8; ++j) r[j] = fmaxf(r[j], 0.f);
  } else {
    float4 rs0 = *reinterpret_cast<const float4*>(&resid[(size_t)node * HID + p8]);
    float4 rs1 = *reinterpret_cast<const float4*>(&resid[(size_t)node * HID + p8 + 4]);
    r[0] += rs0.x; r[1] += rs0.y; r[2] += rs0.z; r[3] += rs0.w;
    r[4] += rs1.x; r[5] += rs1.y; r[6] += rs1.z; r[7] += rs1.w;
  }
  *reinterpret_cast<float4*>(&out[(size_t)node * HID + p8]) =
      make_float4(r[0], r[1], r[2], r[3]);
  *reinterpret_cast<float4*>(&out[(size_t)node * HID + p8 + 4]) =
      make_float4(r[4], r[5], r[6], r[7]);
}

// ============ launcher ============

extern "C" void kernel_launch(void* const* d_in, const int* in_sizes, int n_in,
                              void* d_out, int out_size, void* d_ws, size_t ws_size,
                              hipStream_t stream) {
  const float* x  = (const float*)d_in[0];
  const int*   ei = (const int*)d_in[1];
  const float* ew = (const float*)d_in[2];
  const float* W1 = (const float*)d_in[3];
  const float* b1 = (const float*)d_in[4];
  const float* W2 = (const float*)d_in[5];
  const float* b2 = (const float*)d_in[6];
  float* out = (float*)d_out;

  const int N = in_sizes[0] / DIN;
  const int E = in_sizes[2];
  const int* src = ei;        // ei shape (2,E) row-major
  const int* dst = ei + E;

  const int NBC = (N + 255) >> 8;          // buckets of 256 nodes (196 for N=50000)

  char* p = (char*)d_ws;
  auto carve = [&](size_t bytes) {
    char* r = p;
    p += (bytes + 255) & ~(size_t)255;
    return r;
  };
  // cnt + deg + bsum carved contiguously -> single memset
  int*   cnt    = (int*)carve((size_t)N * 4 + (size_t)N * 4 + 256 * 4);
  float* deg    = (float*)((char*)cnt + (size_t)N * 4);
  int*   bsum   = (int*)((char*)deg + (size_t)N * 4);
  int*   offs   = (int*)carve((size_t)N * 4);
  int*   cur    = (int*)carve((size_t)N * 4);
  float* dinv   = (float*)carve((size_t)N * 4);
  int2*  bufB   = (int2*)carve((size_t)E * 8);        // gapless CSR records
  u16*   h      = (u16*)carve((size_t)N * HID * 2);   // bf16 linear outputs (gathered)
  float* h1     = (float*)carve((size_t)N * HID * 4); // fp32 layer-1 activations
  float* WT1    = (float*)carve((size_t)DIN * HID * 4);
  float* WT2    = (float*)carve((size_t)HID * HID * 4);

  int gblk = (N + 63) / 64;
  int ablk = (N + 31) / 32;                   // 32 nodes per 256-thread block
  int tblk = ((DIN + HID) * 64 + 511) / 512;  // transpose tail blocks

  // ---- front-end: zero counters, count, scan, scatter ----
  hipMemsetAsync(cnt, 0, (size_t)N * 8 + 256 * 4, stream);
  k_cnt<<<KBLK + tblk, 512, 0, stream>>>(dst, ew, cnt, deg, bsum, E, W1, W2, WT1, WT2);
  k_scan<<<NBC, 256, 0, stream>>>(cnt, deg, bsum, offs, cur, dinv, N);
  k_scat<<<SBLK, 512, 0, stream>>>(src, dst, ew, dinv, cur, bufB, E);

  // ---- layer 1 ----
  k_gemm<DIN><<<gblk, 256, 0, stream>>>(x, WT1, h, N);
  k_agg<<<ablk, 256, 0, stream>>>(h, bufB, offs, cnt, dinv, b1, nullptr, h1, N, 0);
  // ---- layer 2 (reuse h buffer for h1 @ W2^T) ----
  k_gemm<HID><<<gblk, 256, 0, stream>>>(h1, WT2, h, N);
  k_agg<<<ablk, 256, 0, stream>>>(h, bufB, offs, cnt, dinv, b2, h1, out, N, 1);
}

// Round 4
// 223.157 us; speedup vs baseline: 1.9310x; 1.9310x over previous
//
#include <hip/hip_runtime.h>

#define HID 64
#define DIN 128
#define NBLK 512                // blocks for the build pass
#define CSH 14                  // slab capacity shift: 16384 entries per bucket
#define CAP (1 << CSH)

typedef unsigned long long ull;
typedef unsigned short u16;

static __device__ __forceinline__ u16 f2bf(float f) {
  unsigned u = __float_as_uint(f);
  unsigned lsb = (u >> 16) & 1u;
  u += 0x7fffu + lsb;
  return (u16)(u >> 16);
}

// ============ K1: fused build — LDS hist + slab reservation + scatter ============
// record int2 = ( float_bits(ew), (src<<16)|dst ). Bucket t's slab = [t<<CSH, ...).
// Per-edge atomics are LDS-only; global atomics = 256 cursor reservations/block.
// (Round-3 lesson: per-edge GLOBAL atomics -> 100MB writeback, 155us. Never.)
// Trailing blocks (b >= NBLK) do the weight transposes (fused launch).

__global__ __launch_bounds__(512) void k_build(const int* __restrict__ src,
                                               const int* __restrict__ dst,
                                               const float* __restrict__ ew,
                                               int* __restrict__ cursor,
                                               int2* __restrict__ bufA,
                                               int E, int NBC, int chunk,
                                               const float* __restrict__ W1,
                                               const float* __restrict__ W2,
                                               float* __restrict__ WT1,
                                               float* __restrict__ WT2) {
  int b = blockIdx.x, tid = threadIdx.x;
  if (b >= NBLK) {               // weight-transpose tail blocks
    int idx = (b - NBLK) * 512 + tid;
    if (idx < DIN * 64) {
      int d = idx >> 6, j = idx & 63;
      WT1[idx] = W1[j * DIN + d];
    }
    int i2 = idx - DIN * 64;
    if (i2 >= 0 && i2 < HID * 64) {
      int d = i2 >> 6, j = i2 & 63;
      WT2[i2] = W2[j * HID + d];
    }
    return;
  }
  __shared__ int h[256];
  __shared__ int cur[256];
  if (tid < 256) h[tid] = 0;
  __syncthreads();
  int e0 = b * chunk, e1 = min(E, e0 + chunk);
  // pass 1: LDS histogram of this chunk
  for (int e = e0 + tid; e < e1; e += 512) atomicAdd(&h[dst[e] >> 8], 1);
  __syncthreads();
  // reserve a contiguous run in each bucket's slab
  if (tid < 256) {
    int c = h[tid];
    int ofs = (c > 0) ? atomicAdd(&cursor[tid], c) : 0;
    cur[tid] = (tid << CSH) + ofs;
  }
  __syncthreads();
  // pass 2: scatter records
  for (int e = e0 + tid; e < e1; e += 512) {
    int s = src[e], d = dst[e];
    float w = ew[e];
    int p = atomicAdd(&cur[d >> 8], 1);
    bufA[p] = make_int2(__float_as_int(w), (int)(((unsigned)s << 16) | (unsigned)d));
  }
}

// ============ K2: one block per coarse bucket -> dst-grouped + offs/cnt + dinv ============
// 1024 threads/block: grid is pinned at NBC=196 (0.77 blocks/CU), so the kernel is
// latency-bound; 16 waves/CU instead of 8 halves the phase trip counts.
// Scatter writes records as (w_bits, src32): norm is FACTORED OUT (applied in k_agg
// as w*dinv[src] per edge and *dinv[dst] on the final sum) -> no k_norm pass.

__global__ __launch_bounds__(1024) void k_passB(const int2* __restrict__ bufA,
                                                const int* __restrict__ cursor,
                                                int2* __restrict__ bufB,
                                                int* __restrict__ offs,
                                                int* __restrict__ cnt,
                                                float* __restrict__ dinv,
                                                int NBC, int N) {
  int bin = blockIdx.x, tid = threadIdx.x;
  __shared__ int h2[256];
  __shared__ int cur[256];
  __shared__ float dg[256];
  int bbase = bin << CSH;
  int m = cursor[bin];
  if (tid < 256) { h2[tid] = 0; dg[tid] = 0.f; }
  __syncthreads();
  // phase 1: fine histogram of dst&255
  for (int i = tid; i < m; i += 1024) {
    unsigned sd = (unsigned)bufA[bbase + i].y;
    atomicAdd(&h2[sd & 255], 1);
  }
  __syncthreads();
  int own = (tid < 256) ? h2[tid] : 0;
  // inclusive Hillis-Steele scan over 256 bins
  for (int o = 1; o < 256; o <<= 1) {
    int u = 0;
    if (tid < 256 && tid >= o) u = h2[tid - o];
    __syncthreads();
    if (tid < 256) h2[tid] += u;
    __syncthreads();
  }
  int nd = (bin << 8) + tid;
  if (tid < 256) {
    int excl = h2[tid] - own;
    cur[tid] = excl;
    if (nd < N) { offs[nd] = bbase + excl; cnt[nd] = own; }
  }
  __syncthreads();
  // phase 2: scatter into dst-grouped order as (w, src) + weighted degree
  for (int i = tid; i < m; i += 1024) {
    int2 r = bufA[bbase + i];
    unsigned sd = (unsigned)r.y;
    int dl = (int)(sd & 255u);
    int p = atomicAdd(&cur[dl], 1);
    bufB[bbase + p] = make_int2(r.x, (int)(sd >> 16));
    atomicAdd(&dg[dl], __int_as_float(r.x));
  }
  __syncthreads();
  if (tid < 256 && nd < N) dinv[nd] = rsqrtf(1.0f + dg[tid]);  // self-loop w=1; deg>=1
}

// ============ K3: GEMM: out[N][64] = X[N][K] @ W[64][K]^T, bf16 output ============
// W pre-transposed (WTg[d][j]); conflict-free float4 LDS staging; inner loop
// 4-wide in d: 8 b128 LDS reads per 64 FMAs -> VALU-bound. (64x64/4x4 measured
// better than 128x64/8x4: 225.4 vs 230.8 us, round-2 data.)

template <int K>
__global__ __launch_bounds__(256) void k_gemm(const float* __restrict__ X,
                                              const float* __restrict__ WTg,
                                              u16* __restrict__ out, int n_nodes) {
  constexpr int PAD = 68;                 // float4-aligned row stride
  __shared__ float XT[64 * PAD];          // XT[m][d]  (row-major)
  __shared__ float WL[64 * PAD];          // WL[d][j]
  const int tid = threadIdx.x;
  const int n0 = blockIdx.x * 64;
  const int tx = tid & 15;                // feature group: j = 4*tx + ji
  const int ty = tid >> 4;                // node group:    m = 4*ty + mi
  float acc[4][4] = {{0.f}};

  for (int ph = 0; ph < K / 64; ++ph) {
    const int d0 = ph * 64;
    __syncthreads();
#pragma unroll
    for (int k = 0; k < 4; ++k) {
      int f = tid + k * 256;              // 0..1023 float4 slots per tile
      int r = f >> 4, q = f & 15;         // r = row, q = float4 column
      int n = n0 + r;
      float4 xv = (n < n_nodes)
        ? *reinterpret_cast<const float4*>(&X[(size_t)n * K + d0 + 4 * q])
        : make_float4(0.f, 0.f, 0.f, 0.f);
      *reinterpret_cast<float4*>(&XT[r * PAD + 4 * q]) = xv;
      float4 wv = *reinterpret_cast<const float4*>(&WTg[(size_t)(d0 + r) * 64 + 4 * q]);
      *reinterpret_cast<float4*>(&WL[r * PAD + 4 * q]) = wv;
    }
    __syncthreads();
#pragma unroll 4
    for (int dd = 0; dd < 64; dd += 4) {
      float4 xs[4], ws[4];
#pragma unroll
      for (int mi = 0; mi < 4; ++mi)
        xs[mi] = *reinterpret_cast<const float4*>(&XT[(4 * ty + mi) * PAD + dd]);
#pragma unroll
      for (int dk = 0; dk < 4; ++dk)
        ws[dk] = *reinterpret_cast<const float4*>(&WL[(dd + dk) * PAD + 4 * tx]);
#pragma unroll
      for (int mi = 0; mi < 4; ++mi) {
        float xm[4] = {xs[mi].x, xs[mi].y, xs[mi].z, xs[mi].w};
#pragma unroll
        for (int dk = 0; dk < 4; ++dk) {
          acc[mi][0] = fmaf(xm[dk], ws[dk].x, acc[mi][0]);
          acc[mi][1] = fmaf(xm[dk], ws[dk].y, acc[mi][1]);
          acc[mi][2] = fmaf(xm[dk], ws[dk].z, acc[mi][2]);
          acc[mi][3] = fmaf(xm[dk], ws[dk].w, acc[mi][3]);
        }
      }
    }
  }

#pragma unroll
  for (int mi = 0; mi < 4; ++mi) {
    int n = n0 + 4 * ty + mi;
    if (n < n_nodes) {
      ushort4 o = make_ushort4(f2bf(acc[mi][0]), f2bf(acc[mi][1]),
                               f2bf(acc[mi][2]), f2bf(acc[mi][3]));
      *reinterpret_cast<ushort4*>(&out[(size_t)n * HID + 4 * tx]) = o;
    }
  }
}

// ============ K4: aggregation v7 — eighth-wave per node, factored norm ============
// Wave = 8 independent 8-lane groups; group g owns one node fully: 8 lanes x
// 8 feats via one 16B (uint4 = 8x bf16) load -> 8 edges per wave-instruction.
// Record = (w_bits, src). Per edge: wd = w * dinv[src] (dinv is 200KB, L2-hot);
// epilogue multiplies edge-sum by dinv[node] once. Self-loop: a initialized to
// h[node] * di, so final di*(...) gives di^2 * h[node].
// mode 0: out = relu(agg + bias)          (layer 1 -> h1, fp32)
// mode 1: out = agg + bias + resid        (layer 2 -> final, fp32)

__device__ __forceinline__ void bfma8(const uint4& v, float w, float* a) {
  a[0] = fmaf(__uint_as_float(v.x << 16), w, a[0]);
  a[1] = fmaf(__uint_as_float(v.x & 0xffff0000u), w, a[1]);
  a[2] = fmaf(__uint_as_float(v.y << 16), w, a[2]);
  a[3] = fmaf(__uint_as_float(v.y & 0xffff0000u), w, a[3]);
  a[4] = fmaf(__uint_as_float(v.z << 16), w, a[4]);
  a[5] = fmaf(__uint_as_float(v.z & 0xffff0000u), w, a[5]);
  a[6] = fmaf(__uint_as_float(v.w << 16), w, a[6]);
  a[7] = fmaf(__uint_as_float(v.w & 0xffff0000u), w, a[7]);
}

__global__ __launch_bounds__(256) void k_agg(const u16* __restrict__ h,
                                             const int2* __restrict__ recs,
                                             const int* __restrict__ offs,
                                             const int* __restrict__ cnt,
                                             const float* __restrict__ dinv,
                                             const float* __restrict__ bias,
                                             const float* __restrict__ resid,
                                             float* __restrict__ out, int n_nodes, int mode) {
  int tid = threadIdx.x;
  int lane = tid & 63;
  int g = lane >> 3;                  // group 0..7
  int p8 = (lane & 7) * 8;            // feature base (8 feats per lane)
  int node = (blockIdx.x * 4 + (tid >> 6)) * 8 + g;   // 32 nodes per block
  if (node >= n_nodes) return;
  int beg = offs[node], end = beg + cnt[node];
  float di = dinv[node];

  float a[8], b[8];
  {
    uint4 v = *reinterpret_cast<const uint4*>(&h[(size_t)node * HID + p8]);
    a[0] = __uint_as_float(v.x << 16) * di;          // self loop: di*(di*h) later
    a[1] = __uint_as_float(v.x & 0xffff0000u) * di;
    a[2] = __uint_as_float(v.y << 16) * di;
    a[3] = __uint_as_float(v.y & 0xffff0000u) * di;
    a[4] = __uint_as_float(v.z << 16) * di;
    a[5] = __uint_as_float(v.z & 0xffff0000u) * di;
    a[6] = __uint_as_float(v.w << 16) * di;
    a[7] = __uint_as_float(v.w & 0xffff0000u) * di;
#pragma unroll
    for (int j = 0; j < 8; ++j) b[j] = 0.f;
  }

  int i = beg;
  while (i + 8 <= end) {              // 8 gathers in flight per group
    int2 r0 = recs[i];     int2 r1 = recs[i + 1];
    int2 r2 = recs[i + 2]; int2 r3 = recs[i + 3];
    int2 r4 = recs[i + 4]; int2 r5 = recs[i + 5];
    int2 r6 = recs[i + 6]; int2 r7 = recs[i + 7];
    uint4 v0 = *reinterpret_cast<const uint4*>(&h[(size_t)r0.y * HID + p8]);
    uint4 v1 = *reinterpret_cast<const uint4*>(&h[(size_t)r1.y * HID + p8]);
    uint4 v2 = *reinterpret_cast<const uint4*>(&h[(size_t)r2.y * HID + p8]);
    uint4 v3 = *reinterpret_cast<const uint4*>(&h[(size_t)r3.y * HID + p8]);
    uint4 v4 = *reinterpret_cast<const uint4*>(&h[(size_t)r4.y * HID + p8]);
    uint4 v5 = *reinterpret_cast<const uint4*>(&h[(size_t)r5.y * HID + p8]);
    uint4 v6 = *reinterpret_cast<const uint4*>(&h[(size_t)r6.y * HID + p8]);
    uint4 v7 = *reinterpret_cast<const uint4*>(&h[(size_t)r7.y * HID + p8]);
    float w0 = __int_as_float(r0.x) * dinv[r0.y];
    float w1 = __int_as_float(r1.x) * dinv[r1.y];
    float w2 = __int_as_float(r2.x) * dinv[r2.y];
    float w3 = __int_as_float(r3.x) * dinv[r3.y];
    float w4 = __int_as_float(r4.x) * dinv[r4.y];
    float w5 = __int_as_float(r5.x) * dinv[r5.y];
    float w6 = __int_as_float(r6.x) * dinv[r6.y];
    float w7 = __int_as_float(r7.x) * dinv[r7.y];
    bfma8(v0, w0, a);
    bfma8(v1, w1, b);
    bfma8(v2, w2, a);
    bfma8(v3, w3, b);
    bfma8(v4, w4, a);
    bfma8(v5, w5, b);
    bfma8(v6, w6, a);
    bfma8(v7, w7, b);
    i += 8;
  }
  if (i + 4 <= end) {
    int2 r0 = recs[i];     int2 r1 = recs[i + 1];
    int2 r2 = recs[i + 2]; int2 r3 = recs[i + 3];
    uint4 v0 = *reinterpret_cast<const uint4*>(&h[(size_t)r0.y * HID + p8]);
    uint4 v1 = *reinterpret_cast<const uint4*>(&h[(size_t)r1.y * HID + p8]);
    uint4 v2 = *reinterpret_cast<const uint4*>(&h[(size_t)r2.y * HID + p8]);
    uint4 v3 = *reinterpret_cast<const uint4*>(&h[(size_t)r3.y * HID + p8]);
    bfma8(v0, __int_as_float(r0.x) * dinv[r0.y], a);
    bfma8(v1, __int_as_float(r1.x) * dinv[r1.y], b);
    bfma8(v2, __int_as_float(r2.x) * dinv[r2.y], a);
    bfma8(v3, __int_as_float(r3.x) * dinv[r3.y], b);
    i += 4;
  }
  if (i + 2 <= end) {
    int2 r0 = recs[i];     int2 r1 = recs[i + 1];
    uint4 v0 = *reinterpret_cast<const uint4*>(&h[(size_t)r0.y * HID + p8]);
    uint4 v1 = *reinterpret_cast<const uint4*>(&h[(size_t)r1.y * HID + p8]);
    bfma8(v0, __int_as_float(r0.x) * dinv[r0.y], a);
    bfma8(v1, __int_as_float(r1.x) * dinv[r1.y], b);
    i += 2;
  }
  if (i < end) {
    int2 r0 = recs[i];
    uint4 v0 = *reinterpret_cast<const uint4*>(&h[(size_t)r0.y * HID + p8]);
    bfma8(v0, __int_as_float(r0.x) * dinv[r0.y], a);
  }

  float r[8];
#pragma unroll
  for (int j = 0; j < 8; ++j) r[j] = (a[j] + b[j]) * di;   // apply dinv[dst] once
  float4 bb0 = *reinterpret_cast<const float4*>(&bias[p8]);
  float4 bb1 = *reinterpret_cast<const float4*>(&bias[p8 + 4]);
  r[0] += bb0.x; r[1] += bb0.y; r[2] += bb0.z; r[3] += bb0.w;
  r[4] += bb1.x; r[5] += bb1.y; r[6] += bb1.z; r[7] += bb1.w;
  if (mode == 0) {
#pragma unroll
    for (int j = 0; j < 8; ++j) r[j] = fmaxf(r[j], 0.f);
  } else {
    float4 rs0 = *reinterpret_cast<const float4*>(&resid[(size_t)node * HID + p8]);
    float4 rs1 = *reinterpret_cast<const float4*>(&resid[(size_t)node * HID + p8 + 4]);
    r[0] += rs0.x; r[1] += rs0.y; r[2] += rs0.z; r[3] += rs0.w;
    r[4] += rs1.x; r[5] += rs1.y; r[6] += rs1.z; r[7] += rs1.w;
  }
  *reinterpret_cast<float4*>(&out[(size_t)node * HID + p8]) =
      make_float4(r[0], r[1], r[2], r[3]);
  *reinterpret_cast<float4*>(&out[(size_t)node * HID + p8 + 4]) =
      make_float4(r[4], r[5], r[6], r[7]);
}

// ============ launcher ============

extern "C" void kernel_launch(void* const* d_in, const int* in_sizes, int n_in,
                              void* d_out, int out_size, void* d_ws, size_t ws_size,
                              hipStream_t stream) {
  const float* x  = (const float*)d_in[0];
  const int*   ei = (const int*)d_in[1];
  const float* ew = (const float*)d_in[2];
  const float* W1 = (const float*)d_in[3];
  const float* b1 = (const float*)d_in[4];
  const float* W2 = (const float*)d_in[5];
  const float* b2 = (const float*)d_in[6];
  float* out = (float*)d_out;

  const int N = in_sizes[0] / DIN;
  const int E = in_sizes[2];
  const int* src = ei;        // ei shape (2,E) row-major
  const int* dst = ei + E;

  const int NBC = (N + 255) >> 8;          // coarse buckets (196 for N=50000)
  const int chunk = (E + NBLK - 1) / NBLK;
  const int nslab = NBC << CSH;            // total slab entries

  char* p = (char*)d_ws;
  auto carve = [&](size_t bytes) {
    char* r = p;
    p += (bytes + 255) & ~(size_t)255;
    return r;
  };
  int*   cursor = (int*)carve(256 * 4);
  int*   offs   = (int*)carve((size_t)N * 4);
  int*   cnt    = (int*)carve((size_t)N * 4);
  float* dinv   = (float*)carve((size_t)N * 4);
  int2*  bufA   = (int2*)carve((size_t)nslab * 8);
  int2*  bufB   = (int2*)carve((size_t)nslab * 8);
  u16*   h      = (u16*)carve((size_t)N * HID * 2);   // bf16 linear outputs (gathered)
  float* h1     = (float*)carve((size_t)N * HID * 4); // fp32 layer-1 activations
  float* WT1    = (float*)carve((size_t)DIN * HID * 4);
  float* WT2    = (float*)carve((size_t)HID * HID * 4);

  int gblk = (N + 63) / 64;
  int ablk = (N + 31) / 32;                   // 32 nodes per 256-thread block
  int tblk = ((DIN + HID) * 64 + 511) / 512;  // transpose tail blocks

  // ---- build: memset + fused hist/reserve/scatter + bucket sort (norm folded) ----
  hipMemsetAsync(cursor, 0, 256 * 4, stream);
  k_build<<<NBLK + tblk, 512, 0, stream>>>(src, dst, ew, cursor, bufA, E, NBC, chunk,
                                           W1, W2, WT1, WT2);
  k_passB<<<NBC, 1024, 0, stream>>>(bufA, cursor, bufB, offs, cnt, dinv, NBC, N);

  // ---- layer 1 ----
  k_gemm<DIN><<<gblk, 256, 0, stream>>>(x, WT1, h, N);
  k_agg<<<ablk, 256, 0, stream>>>(h, bufB, offs, cnt, dinv, b1, nullptr, h1, N, 0);
  // ---- layer 2 (reuse h buffer for h1 @ W2^T) ----
  k_gemm<HID><<<gblk, 256, 0, stream>>>(h1, WT2, h, N);
  k_agg<<<ablk, 256, 0, stream>>>(h, bufB, offs, cnt, dinv, b2, h1, out, N, 1);
}

// Round 5
// 221.807 us; speedup vs baseline: 1.9427x; 1.0061x over previous
//
#include <hip/hip_runtime.h>

#define HID 64
#define DIN 128
#define NBLK 512                // blocks for the build pass
#define CSH 14                  // slab capacity shift: 16384 entries per bucket
#define CAP (1 << CSH)

typedef unsigned long long ull;
typedef unsigned short u16;

static __device__ __forceinline__ u16 f2bf(float f) {
  unsigned u = __float_as_uint(f);
  unsigned lsb = (u >> 16) & 1u;
  u += 0x7fffu + lsb;
  return (u16)(u >> 16);
}

// ============ K1: fused build — LDS hist + slab reservation + scatter ============
// record int2 = ( float_bits(ew), (src<<16)|dst ). Bucket t's slab = [t<<CSH, ...).
// Per-edge atomics are LDS-only; global atomics = 256 cursor reservations/block.
// (Round-3 lesson: per-edge GLOBAL atomics -> 100MB writeback, 155us. Never.)
// Trailing blocks (b >= NBLK) do the weight transposes (fused launch).

__global__ __launch_bounds__(512) void k_build(const int* __restrict__ src,
                                               const int* __restrict__ dst,
                                               const float* __restrict__ ew,
                                               int* __restrict__ cursor,
                                               int2* __restrict__ bufA,
                                               int E, int NBC, int chunk,
                                               const float* __restrict__ W1,
                                               const float* __restrict__ W2,
                                               float* __restrict__ WT1,
                                               float* __restrict__ WT2) {
  int b = blockIdx.x, tid = threadIdx.x;
  if (b >= NBLK) {               // weight-transpose tail blocks
    int idx = (b - NBLK) * 512 + tid;
    if (idx < DIN * 64) {
      int d = idx >> 6, j = idx & 63;
      WT1[idx] = W1[j * DIN + d];
    }
    int i2 = idx - DIN * 64;
    if (i2 >= 0 && i2 < HID * 64) {
      int d = i2 >> 6, j = i2 & 63;
      WT2[i2] = W2[j * HID + d];
    }
    return;
  }
  __shared__ int h[256];
  __shared__ int cur[256];
  if (tid < 256) h[tid] = 0;
  __syncthreads();
  int e0 = b * chunk, e1 = min(E, e0 + chunk);
  // pass 1: LDS histogram of this chunk
  for (int e = e0 + tid; e < e1; e += 512) atomicAdd(&h[dst[e] >> 8], 1);
  __syncthreads();
  // reserve a contiguous run in each bucket's slab
  if (tid < 256) {
    int c = h[tid];
    int ofs = (c > 0) ? atomicAdd(&cursor[tid], c) : 0;
    cur[tid] = (tid << CSH) + ofs;
  }
  __syncthreads();
  // pass 2: scatter records
  for (int e = e0 + tid; e < e1; e += 512) {
    int s = src[e], d = dst[e];
    float w = ew[e];
    int p = atomicAdd(&cur[d >> 8], 1);
    bufA[p] = make_int2(__float_as_int(w), (int)(((unsigned)s << 16) | (unsigned)d));
  }
}

// ============ K2: one block per coarse bucket -> dst-grouped + offs/cnt + dinv ============
// 1024 threads/block, one block per bucket (grid pinned at NBC=196 -> latency-bound,
// so maximize waves). Records cached in registers across the two phases: bufA is
// read ONCE (m <= CAP=16384 -> <=16 records/thread). Output record = (w_bits, src);
// norm is factored out (dinv baked into gemm output h', final *dinv[dst] in agg).

__global__ __launch_bounds__(1024) void k_passB(const int2* __restrict__ bufA,
                                                const int* __restrict__ cursor,
                                                int2* __restrict__ bufB,
                                                int* __restrict__ offs,
                                                int* __restrict__ cnt,
                                                float* __restrict__ dinv,
                                                int NBC, int N) {
  int bin = blockIdx.x, tid = threadIdx.x;
  __shared__ int h2[256];
  __shared__ int cur[256];
  __shared__ float dg[256];
  int bbase = bin << CSH;
  int m = cursor[bin];
  if (tid < 256) { h2[tid] = 0; dg[tid] = 0.f; }
  __syncthreads();
  // phase 1: fine histogram of dst&255, records cached in registers
  int2 rloc[16];                 // CAP/1024 = 16 max records per thread
#pragma unroll
  for (int k = 0; k < 16; ++k) {
    int i = tid + k * 1024;
    if (i < m) {
      rloc[k] = bufA[bbase + i];
      atomicAdd(&h2[(unsigned)rloc[k].y & 255u], 1);
    }
  }
  __syncthreads();
  int own = (tid < 256) ? h2[tid] : 0;
  // inclusive Hillis-Steele scan over 256 bins
  for (int o = 1; o < 256; o <<= 1) {
    int u = 0;
    if (tid < 256 && tid >= o) u = h2[tid - o];
    __syncthreads();
    if (tid < 256) h2[tid] += u;
    __syncthreads();
  }
  int nd = (bin << 8) + tid;
  if (tid < 256) {
    int excl = h2[tid] - own;
    cur[tid] = excl;
    if (nd < N) { offs[nd] = bbase + excl; cnt[nd] = own; }
  }
  __syncthreads();
  // phase 2: scatter into dst-grouped order as (w, src) + weighted degree
#pragma unroll
  for (int k = 0; k < 16; ++k) {
    int i = tid + k * 1024;
    if (i < m) {
      int2 r = rloc[k];
      unsigned sd = (unsigned)r.y;
      int dl = (int)(sd & 255u);
      int p = atomicAdd(&cur[dl], 1);
      bufB[bbase + p] = make_int2(r.x, (int)(sd >> 16));
      atomicAdd(&dg[dl], __int_as_float(r.x));
    }
  }
  __syncthreads();
  if (tid < 256 && nd < N) dinv[nd] = rsqrtf(1.0f + dg[tid]);  // self-loop w=1; deg>=1
}

// ============ K3: GEMM: out[N][64] = dinv[n] * (X[N][K] @ W[64][K]^T), bf16 ============
// dinv is BAKED into the output row (h' = dinv*X*W^T): the aggregation then needs
// no per-edge dinv gather (edge term = w * h'[src]; self = h'[node]; *dinv[dst] once).
// W pre-transposed (WTg[d][j]); conflict-free float4 LDS staging; inner loop
// 4-wide in d: 8 b128 LDS reads per 64 FMAs. (64x64/4x4 beat 128x64/8x4, round-2.)

template <int K>
__global__ __launch_bounds__(256) void k_gemm(const float* __restrict__ X,
                                              const float* __restrict__ WTg,
                                              const float* __restrict__ dinv,
                                              u16* __restrict__ out, int n_nodes) {
  constexpr int PAD = 68;                 // float4-aligned row stride
  __shared__ float XT[64 * PAD];          // XT[m][d]  (row-major)
  __shared__ float WL[64 * PAD];          // WL[d][j]
  const int tid = threadIdx.x;
  const int n0 = blockIdx.x * 64;
  const int tx = tid & 15;                // feature group: j = 4*tx + ji
  const int ty = tid >> 4;                // node group:    m = 4*ty + mi
  float acc[4][4] = {{0.f}};

  for (int ph = 0; ph < K / 64; ++ph) {
    const int d0 = ph * 64;
    __syncthreads();
#pragma unroll
    for (int k = 0; k < 4; ++k) {
      int f = tid + k * 256;              // 0..1023 float4 slots per tile
      int r = f >> 4, q = f & 15;         // r = row, q = float4 column
      int n = n0 + r;
      float4 xv = (n < n_nodes)
        ? *reinterpret_cast<const float4*>(&X[(size_t)n * K + d0 + 4 * q])
        : make_float4(0.f, 0.f, 0.f, 0.f);
      *reinterpret_cast<float4*>(&XT[r * PAD + 4 * q]) = xv;
      float4 wv = *reinterpret_cast<const float4*>(&WTg[(size_t)(d0 + r) * 64 + 4 * q]);
      *reinterpret_cast<float4*>(&WL[r * PAD + 4 * q]) = wv;
    }
    __syncthreads();
#pragma unroll 4
    for (int dd = 0; dd < 64; dd += 4) {
      float4 xs[4], ws[4];
#pragma unroll
      for (int mi = 0; mi < 4; ++mi)
        xs[mi] = *reinterpret_cast<const float4*>(&XT[(4 * ty + mi) * PAD + dd]);
#pragma unroll
      for (int dk = 0; dk < 4; ++dk)
        ws[dk] = *reinterpret_cast<const float4*>(&WL[(dd + dk) * PAD + 4 * tx]);
#pragma unroll
      for (int mi = 0; mi < 4; ++mi) {
        float xm[4] = {xs[mi].x, xs[mi].y, xs[mi].z, xs[mi].w};
#pragma unroll
        for (int dk = 0; dk < 4; ++dk) {
          acc[mi][0] = fmaf(xm[dk], ws[dk].x, acc[mi][0]);
          acc[mi][1] = fmaf(xm[dk], ws[dk].y, acc[mi][1]);
          acc[mi][2] = fmaf(xm[dk], ws[dk].z, acc[mi][2]);
          acc[mi][3] = fmaf(xm[dk], ws[dk].w, acc[mi][3]);
        }
      }
    }
  }

#pragma unroll
  for (int mi = 0; mi < 4; ++mi) {
    int n = n0 + 4 * ty + mi;
    if (n < n_nodes) {
      float dn = dinv[n];
      ushort4 o = make_ushort4(f2bf(acc[mi][0] * dn), f2bf(acc[mi][1] * dn),
                               f2bf(acc[mi][2] * dn), f2bf(acc[mi][3] * dn));
      *reinterpret_cast<ushort4*>(&out[(size_t)n * HID + 4 * tx]) = o;
    }
  }
}

// ============ K4: aggregation v8 — eighth-wave per node, shfl-shared records ============
// Wave = 8 independent 8-lane groups; group g owns one node: 8 lanes x 8 feats.
// h' rows already carry dinv[src], so per edge: just w * h'[src] (no dinv gather).
// Main loop: ONE record load per 8 edges (lane l loads recs[i+(l&7)], 64B/group,
// one wave-inst) and (w,src) redistributed via 64-bit __shfl -> 9 memory
// wave-inst per 8 edges (was 24). Epilogue multiplies by dinv[node] once.
// mode 0: out = relu(agg + bias)          (layer 1 -> h1, fp32)
// mode 1: out = agg + bias + resid        (layer 2 -> final, fp32)

__device__ __forceinline__ void bfma8(const uint4& v, float w, float* a) {
  a[0] = fmaf(__uint_as_float(v.x << 16), w, a[0]);
  a[1] = fmaf(__uint_as_float(v.x & 0xffff0000u), w, a[1]);
  a[2] = fmaf(__uint_as_float(v.y << 16), w, a[2]);
  a[3] = fmaf(__uint_as_float(v.y & 0xffff0000u), w, a[3]);
  a[4] = fmaf(__uint_as_float(v.z << 16), w, a[4]);
  a[5] = fmaf(__uint_as_float(v.z & 0xffff0000u), w, a[5]);
  a[6] = fmaf(__uint_as_float(v.w << 16), w, a[6]);
  a[7] = fmaf(__uint_as_float(v.w & 0xffff0000u), w, a[7]);
}

__global__ __launch_bounds__(256) void k_agg(const u16* __restrict__ h,
                                             const int2* __restrict__ recs,
                                             const int* __restrict__ offs,
                                             const int* __restrict__ cnt,
                                             const float* __restrict__ dinv,
                                             const float* __restrict__ bias,
                                             const float* __restrict__ resid,
                                             float* __restrict__ out, int n_nodes, int mode) {
  int tid = threadIdx.x;
  int lane = tid & 63;
  int g = lane >> 3;                  // group 0..7
  int p8 = (lane & 7) * 8;            // feature base (8 feats per lane)
  int node = (blockIdx.x * 4 + (tid >> 6)) * 8 + g;   // 32 nodes per block
  if (node >= n_nodes) return;
  int beg = offs[node], end = beg + cnt[node];
  float di = dinv[node];

  float a[8], b[8];
  {
    uint4 v = *reinterpret_cast<const uint4*>(&h[(size_t)node * HID + p8]);
    a[0] = __uint_as_float(v.x << 16);          // self loop: h'[node] (dinv baked)
    a[1] = __uint_as_float(v.x & 0xffff0000u);
    a[2] = __uint_as_float(v.y << 16);
    a[3] = __uint_as_float(v.y & 0xffff0000u);
    a[4] = __uint_as_float(v.z << 16);
    a[5] = __uint_as_float(v.z & 0xffff0000u);
    a[6] = __uint_as_float(v.w << 16);
    a[7] = __uint_as_float(v.w & 0xffff0000u);
#pragma unroll
    for (int j = 0; j < 8; ++j) b[j] = 0.f;
  }

  const int gb = lane & 56;           // group base lane
  int i = beg;
  while (i + 8 <= end) {              // 8 edges per iteration, 1 record wave-load
    ull rr = *reinterpret_cast<const ull*>(&recs[i + (lane & 7)]);
#pragma unroll
    for (int k = 0; k < 8; ++k) {
      ull q = __shfl(rr, gb | k, 64);
      float wk = __uint_as_float((unsigned)q);
      int sk = (int)(q >> 32);
      uint4 vk = *reinterpret_cast<const uint4*>(&h[(size_t)sk * HID + p8]);
      bfma8(vk, wk, (k & 1) ? b : a);
    }
    i += 8;
  }
  if (i + 4 <= end) {
    int2 r0 = recs[i];     int2 r1 = recs[i + 1];
    int2 r2 = recs[i + 2]; int2 r3 = recs[i + 3];
    uint4 v0 = *reinterpret_cast<const uint4*>(&h[(size_t)r0.y * HID + p8]);
    uint4 v1 = *reinterpret_cast<const uint4*>(&h[(size_t)r1.y * HID + p8]);
    uint4 v2 = *reinterpret_cast<const uint4*>(&h[(size_t)r2.y * HID + p8]);
    uint4 v3 = *reinterpret_cast<const uint4*>(&h[(size_t)r3.y * HID + p8]);
    bfma8(v0, __int_as_float(r0.x), a);
    bfma8(v1, __int_as_float(r1.x), b);
    bfma8(v2, __int_as_float(r2.x), a);
    bfma8(v3, __int_as_float(r3.x), b);
    i += 4;
  }
  if (i + 2 <= end) {
    int2 r0 = recs[i];     int2 r1 = recs[i + 1];
    uint4 v0 = *reinterpret_cast<const uint4*>(&h[(size_t)r0.y * HID + p8]);
    uint4 v1 = *reinterpret_cast<const uint4*>(&h[(size_t)r1.y * HID + p8]);
    bfma8(v0, __int_as_float(r0.x), a);
    bfma8(v1, __int_as_float(r1.x), b);
    i += 2;
  }
  if (i < end) {
    int2 r0 = recs[i];
    uint4 v0 = *reinterpret_cast<const uint4*>(&h[(size_t)r0.y * HID + p8]);
    bfma8(v0, __int_as_float(r0.x), a);
  }

  float r[8];
#pragma unroll
  for (int j = 0; j < 8; ++j) r[j] = (a[j] + b[j]) * di;   // apply dinv[dst] once
  float4 bb0 = *reinterpret_cast<const float4*>(&bias[p8]);
  float4 bb1 = *reinterpret_cast<const float4*>(&bias[p8 + 4]);
  r[0] += bb0.x; r[1] += bb0.y; r[2] += bb0.z; r[3] += bb0.w;
  r[4] += bb1.x; r[5] += bb1.y; r[6] += bb1.z; r[7] += bb1.w;
  if (mode == 0) {
#pragma unroll
    for (int j = 0; j < 8; ++j) r[j] = fmaxf(r[j], 0.f);
  } else {
    float4 rs0 = *reinterpret_cast<const float4*>(&resid[(size_t)node * HID + p8]);
    float4 rs1 = *reinterpret_cast<const float4*>(&resid[(size_t)node * HID + p8 + 4]);
    r[0] += rs0.x; r[1] += rs0.y; r[2] += rs0.z; r[3] += rs0.w;
    r[4] += rs1.x; r[5] += rs1.y; r[6] += rs1.z; r[7] += rs1.w;
  }
  *reinterpret_cast<float4*>(&out[(size_t)node * HID + p8]) =
      make_float4(r[0], r[1], r[2], r[3]);
  *reinterpret_cast<float4*>(&out[(size_t)node * HID + p8 + 4]) =
      make_float4(r[4], r[5], r[6], r[7]);
}

// ============ launcher ============

extern "C" void kernel_launch(void* const* d_in, const int* in_sizes, int n_in,
                              void* d_out, int out_size, void* d_ws, size_t ws_size,
                              hipStream_t stream) {
  const float* x  = (const float*)d_in[0];
  const int*   ei = (const int*)d_in[1];
  const float* ew = (const float*)d_in[2];
  const float* W1 = (const float*)d_in[3];
  const float* b1 = (const float*)d_in[4];
  const float* W2 = (const float*)d_in[5];
  const float* b2 = (const float*)d_in[6];
  float* out = (float*)d_out;

  const int N = in_sizes[0] / DIN;
  const int E = in_sizes[2];
  const int* src = ei;        // ei shape (2,E) row-major
  const int* dst = ei + E;

  const int NBC = (N + 255) >> 8;          // coarse buckets (196 for N=50000)
  const int chunk = (E + NBLK - 1) / NBLK;
  const int nslab = NBC << CSH;            // total slab entries

  char* p = (char*)d_ws;
  auto carve = [&](size_t bytes) {
    char* r = p;
    p += (bytes + 255) & ~(size_t)255;
    return r;
  };
  int*   cursor = (int*)carve(256 * 4);
  int*   offs   = (int*)carve((size_t)N * 4);
  int*   cnt    = (int*)carve((size_t)N * 4);
  float* dinv   = (float*)carve((size_t)N * 4);
  int2*  bufA   = (int2*)carve((size_t)nslab * 8);
  int2*  bufB   = (int2*)carve((size_t)nslab * 8);
  u16*   h      = (u16*)carve((size_t)N * HID * 2);   // bf16 h' = dinv * (X@W^T)
  float* h1     = (float*)carve((size_t)N * HID * 4); // fp32 layer-1 activations
  float* WT1    = (float*)carve((size_t)DIN * HID * 4);
  float* WT2    = (float*)carve((size_t)HID * HID * 4);

  int gblk = (N + 63) / 64;
  int ablk = (N + 31) / 32;                   // 32 nodes per 256-thread block
  int tblk = ((DIN + HID) * 64 + 511) / 512;  // transpose tail blocks

  // ---- build: memset + fused hist/reserve/scatter + bucket sort ----
  hipMemsetAsync(cursor, 0, 256 * 4, stream);
  k_build<<<NBLK + tblk, 512, 0, stream>>>(src, dst, ew, cursor, bufA, E, NBC, chunk,
                                           W1, W2, WT1, WT2);
  k_passB<<<NBC, 1024, 0, stream>>>(bufA, cursor, bufB, offs, cnt, dinv, NBC, N);

  // ---- layer 1 ----
  k_gemm<DIN><<<gblk, 256, 0, stream>>>(x, WT1, dinv, h, N);
  k_agg<<<ablk, 256, 0, stream>>>(h, bufB, offs, cnt, dinv, b1, nullptr, h1, N, 0);
  // ---- layer 2 (reuse h buffer for h1 @ W2^T) ----
  k_gemm<HID><<<gblk, 256, 0, stream>>>(h1, WT2, dinv, h, N);
  k_agg<<<ablk, 256, 0, stream>>>(h, bufB, offs, cnt, dinv, b2, h1, out, N, 1);
}

// Round 6
// 216.105 us; speedup vs baseline: 1.9940x; 1.0264x over previous
//
#include <hip/hip_runtime.h>

#define HID 64
#define DIN 128
#define NBLK 512                // blocks for the build pass
#define CSH 14                  // slab capacity shift: 16384 entries per bucket
#define CAP (1 << CSH)
#define PAD 68                  // float4-aligned LDS row stride

typedef unsigned long long ull;
typedef unsigned short u16;

static __device__ __forceinline__ u16 f2bf(float f) {
  unsigned u = __float_as_uint(f);
  unsigned lsb = (u >> 16) & 1u;
  u += 0x7fffu + lsb;
  return (u16)(u >> 16);
}

// ============ shared gemm tile: 512 threads, 64x64 output, self-transposing W ====
// out[n0+m][j] = sum_d X[n0+m][d] * W[j][d];  m = ty, ty+32; j = 4*tx..4*tx+3.
// W (row-major [64][K]) is transposed into WL[d][j] during staging (float4 global
// read + 4 scalar LDS writes). XT_PRELOADED: XT was filled by the caller (fused
// agg epilogue) -> skip X staging. Store guarded by n < n_nodes; bf16 output.

template <int K, bool XT_PRELOADED>
__device__ __forceinline__ void gemm_tile(const float* __restrict__ X,
                                          const float* __restrict__ W,
                                          u16* __restrict__ out,
                                          float* XT, float* WL,
                                          int n0, int n_nodes, int tid) {
  const int tx = tid & 15;
  const int ty = tid >> 4;                // 0..31
  float acc[2][4] = {{0.f}};

  for (int ph = 0; ph < K / 64; ++ph) {
    const int d0 = ph * 64;
    __syncthreads();
    if (!XT_PRELOADED) {
#pragma unroll
      for (int k = 0; k < 2; ++k) {
        int f = tid + k * 512;            // 1024 float4 slots: 64 rows x 16 quads
        int r = f >> 4, q = f & 15;
        int n = n0 + r;
        float4 xv = (n < n_nodes)
          ? *reinterpret_cast<const float4*>(&X[(size_t)n * K + d0 + 4 * q])
          : make_float4(0.f, 0.f, 0.f, 0.f);
        *reinterpret_cast<float4*>(&XT[r * PAD + 4 * q]) = xv;
      }
    }
#pragma unroll
    for (int k = 0; k < 2; ++k) {
      int gq = tid + k * 512;             // 1024 slots: 64 j-rows x 16 d-quads
      int j = gq >> 4, qd = gq & 15;
      float4 wv = *reinterpret_cast<const float4*>(&W[(size_t)j * K + d0 + 4 * qd]);
      WL[(4 * qd + 0) * PAD + j] = wv.x;
      WL[(4 * qd + 1) * PAD + j] = wv.y;
      WL[(4 * qd + 2) * PAD + j] = wv.z;
      WL[(4 * qd + 3) * PAD + j] = wv.w;
    }
    __syncthreads();
#pragma unroll 4
    for (int dd = 0; dd < 64; dd += 4) {
      float4 ws[4];
#pragma unroll
      for (int dk = 0; dk < 4; ++dk)
        ws[dk] = *reinterpret_cast<const float4*>(&WL[(dd + dk) * PAD + 4 * tx]);
      float4 x0 = *reinterpret_cast<const float4*>(&XT[ty * PAD + dd]);
      float4 x1 = *reinterpret_cast<const float4*>(&XT[(ty + 32) * PAD + dd]);
      float xm0[4] = {x0.x, x0.y, x0.z, x0.w};
      float xm1[4] = {x1.x, x1.y, x1.z, x1.w};
#pragma unroll
      for (int dk = 0; dk < 4; ++dk) {
        acc[0][0] = fmaf(xm0[dk], ws[dk].x, acc[0][0]);
        acc[0][1] = fmaf(xm0[dk], ws[dk].y, acc[0][1]);
        acc[0][2] = fmaf(xm0[dk], ws[dk].z, acc[0][2]);
        acc[0][3] = fmaf(xm0[dk], ws[dk].w, acc[0][3]);
        acc[1][0] = fmaf(xm1[dk], ws[dk].x, acc[1][0]);
        acc[1][1] = fmaf(xm1[dk], ws[dk].y, acc[1][1]);
        acc[1][2] = fmaf(xm1[dk], ws[dk].z, acc[1][2]);
        acc[1][3] = fmaf(xm1[dk], ws[dk].w, acc[1][3]);
      }
    }
  }

#pragma unroll
  for (int mi = 0; mi < 2; ++mi) {
    int n = n0 + mi * 32 + ty;
    if (n < n_nodes) {
      ushort4 o = make_ushort4(f2bf(acc[mi][0]), f2bf(acc[mi][1]),
                               f2bf(acc[mi][2]), f2bf(acc[mi][3]));
      *reinterpret_cast<ushort4*>(&out[(size_t)n * HID + 4 * tx]) = o;
    }
  }
}

// ============ K1: fused build + layer-1 GEMM (independent block roles) ============
// b < NBLK: edge build (LDS hist + slab reservation + scatter; per-edge atomics
// LDS-only — round-3 lesson: per-edge GLOBAL atomics = 100MB writeback, never).
// b >= NBLK: 64x64 gemm1 tile h = x@W1^T (bf16, dinv NOT baked — not ready yet).
// The two roles share one LDS allocation and co-schedule across CUs.

__global__ __launch_bounds__(512) void k_build_gemm(const int* __restrict__ src,
                                                    const int* __restrict__ dst,
                                                    const float* __restrict__ ew,
                                                    int* __restrict__ cursor,
                                                    int2* __restrict__ bufA,
                                                    int E, int chunk,
                                                    const float* __restrict__ x,
                                                    const float* __restrict__ W1,
                                                    u16* __restrict__ h,
                                                    int n_nodes) {
  __shared__ float S[2 * 64 * PAD];
  int b = blockIdx.x, tid = threadIdx.x;
  if (b >= NBLK) {               // gemm1 tile blocks
    gemm_tile<DIN, false>(x, W1, h, S, S + 64 * PAD, (b - NBLK) * 64, n_nodes, tid);
    return;
  }
  int* hst = (int*)S;
  int* cur = (int*)S + 256;
  if (tid < 256) hst[tid] = 0;
  __syncthreads();
  int e0 = b * chunk, e1 = min(E, e0 + chunk);
  // pass 1: LDS histogram of this chunk
  for (int e = e0 + tid; e < e1; e += 512) atomicAdd(&hst[dst[e] >> 8], 1);
  __syncthreads();
  // reserve a contiguous run in each bucket's slab
  if (tid < 256) {
    int c = hst[tid];
    int ofs = (c > 0) ? atomicAdd(&cursor[tid], c) : 0;
    cur[tid] = (tid << CSH) + ofs;
  }
  __syncthreads();
  // pass 2: scatter records
  for (int e = e0 + tid; e < e1; e += 512) {
    int s = src[e], d = dst[e];
    float w = ew[e];
    int p = atomicAdd(&cur[d >> 8], 1);
    bufA[p] = make_int2(__float_as_int(w), (int)(((unsigned)s << 16) | (unsigned)d));
  }
}

// ============ K2: one block per coarse bucket -> dst-grouped + offs/cnt + dinv ============
// 1024 threads/block (grid pinned at NBC=196 -> latency-bound, maximize waves).
// Records cached in registers across the two phases: bufA read ONCE.
// Output record = (w_bits, src); norm factored (w*dinv[src] in agg, *dinv[dst] once).

__global__ __launch_bounds__(1024) void k_passB(const int2* __restrict__ bufA,
                                                const int* __restrict__ cursor,
                                                int2* __restrict__ bufB,
                                                int* __restrict__ offs,
                                                int* __restrict__ cnt,
                                                float* __restrict__ dinv,
                                                int NBC, int N) {
  int bin = blockIdx.x, tid = threadIdx.x;
  __shared__ int h2[256];
  __shared__ int cur[256];
  __shared__ float dg[256];
  int bbase = bin << CSH;
  int m = cursor[bin];
  if (tid < 256) { h2[tid] = 0; dg[tid] = 0.f; }
  __syncthreads();
  // phase 1: fine histogram of dst&255, records cached in registers
  int2 rloc[16];                 // CAP/1024 = 16 max records per thread
#pragma unroll
  for (int k = 0; k < 16; ++k) {
    int i = tid + k * 1024;
    if (i < m) {
      rloc[k] = bufA[bbase + i];
      atomicAdd(&h2[(unsigned)rloc[k].y & 255u], 1);
    }
  }
  __syncthreads();
  int own = (tid < 256) ? h2[tid] : 0;
  // inclusive Hillis-Steele scan over 256 bins
  for (int o = 1; o < 256; o <<= 1) {
    int u = 0;
    if (tid < 256 && tid >= o) u = h2[tid - o];
    __syncthreads();
    if (tid < 256) h2[tid] += u;
    __syncthreads();
  }
  int nd = (bin << 8) + tid;
  if (tid < 256) {
    int excl = h2[tid] - own;
    cur[tid] = excl;
    if (nd < N) { offs[nd] = bbase + excl; cnt[nd] = own; }
  }
  __syncthreads();
  // phase 2: scatter into dst-grouped order as (w, src) + weighted degree
#pragma unroll
  for (int k = 0; k < 16; ++k) {
    int i = tid + k * 1024;
    if (i < m) {
      int2 r = rloc[k];
      unsigned sd = (unsigned)r.y;
      int dl = (int)(sd & 255u);
      int p = atomicAdd(&cur[dl], 1);
      bufB[bbase + p] = make_int2(r.x, (int)(sd >> 16));
      atomicAdd(&dg[dl], __int_as_float(r.x));
    }
  }
  __syncthreads();
  if (tid < 256 && nd < N) dinv[nd] = rsqrtf(1.0f + dg[tid]);  // self-loop w=1; deg>=1
}

// ============ agg core: 8-lane group per node, shfl-shared records ============
// Per 8 edges: one 64B record wave-load; lane pre-multiplies w*dinv[src] (1 L2-hot
// gather), 64-bit shfl redistributes. a/b dual accumulators for FMA ILP.

__device__ __forceinline__ void bfma8(const uint4& v, float w, float* a) {
  a[0] = fmaf(__uint_as_float(v.x << 16), w, a[0]);
  a[1] = fmaf(__uint_as_float(v.x & 0xffff0000u), w, a[1]);
  a[2] = fmaf(__uint_as_float(v.y << 16), w, a[2]);
  a[3] = fmaf(__uint_as_float(v.y & 0xffff0000u), w, a[3]);
  a[4] = fmaf(__uint_as_float(v.z << 16), w, a[4]);
  a[5] = fmaf(__uint_as_float(v.z & 0xffff0000u), w, a[5]);
  a[6] = fmaf(__uint_as_float(v.w << 16), w, a[6]);
  a[7] = fmaf(__uint_as_float(v.w & 0xffff0000u), w, a[7]);
}

// accumulates di*(sum_e w*dinv[s]*h[s] + di*h[node]) into r[8] (pre-bias)
__device__ __forceinline__ void agg_node(const u16* __restrict__ h,
                                         const int2* __restrict__ recs,
                                         const float* __restrict__ dinv,
                                         int beg, int end, int node, float di,
                                         int lane, int p8, float* r) {
  float a[8], b[8];
  {
    uint4 v = *reinterpret_cast<const uint4*>(&h[(size_t)node * HID + p8]);
    a[0] = __uint_as_float(v.x << 16) * di;          // self: di*(di*h) after epilogue
    a[1] = __uint_as_float(v.x & 0xffff0000u) * di;
    a[2] = __uint_as_float(v.y << 16) * di;
    a[3] = __uint_as_float(v.y & 0xffff0000u) * di;
    a[4] = __uint_as_float(v.z << 16) * di;
    a[5] = __uint_as_float(v.z & 0xffff0000u) * di;
    a[6] = __uint_as_float(v.w << 16) * di;
    a[7] = __uint_as_float(v.w & 0xffff0000u) * di;
#pragma unroll
    for (int j = 0; j < 8; ++j) b[j] = 0.f;
  }

  const int gb = lane & 56;           // group base lane
  int i = beg;
  while (i + 8 <= end) {              // 8 edges per iteration, 1 record wave-load
    ull rr = *reinterpret_cast<const ull*>(&recs[i + (lane & 7)]);
    float wd = __uint_as_float((unsigned)rr) * dinv[(int)(rr >> 32)];
    rr = (rr & 0xffffffff00000000ull) | (ull)__float_as_uint(wd);
#pragma unroll
    for (int k = 0; k < 8; ++k) {
      ull q = __shfl(rr, gb | k, 64);
      float wk = __uint_as_float((unsigned)q);
      int sk = (int)(q >> 32);
      uint4 vk = *reinterpret_cast<const uint4*>(&h[(size_t)sk * HID + p8]);
      bfma8(vk, wk, (k & 1) ? b : a);
    }
    i += 8;
  }
  if (i + 4 <= end) {
    int2 r0 = recs[i];     int2 r1 = recs[i + 1];
    int2 r2 = recs[i + 2]; int2 r3 = recs[i + 3];
    uint4 v0 = *reinterpret_cast<const uint4*>(&h[(size_t)r0.y * HID + p8]);
    uint4 v1 = *reinterpret_cast<const uint4*>(&h[(size_t)r1.y * HID + p8]);
    uint4 v2 = *reinterpret_cast<const uint4*>(&h[(size_t)r2.y * HID + p8]);
    uint4 v3 = *reinterpret_cast<const uint4*>(&h[(size_t)r3.y * HID + p8]);
    bfma8(v0, __int_as_float(r0.x) * dinv[r0.y], a);
    bfma8(v1, __int_as_float(r1.x) * dinv[r1.y], b);
    bfma8(v2, __int_as_float(r2.x) * dinv[r2.y], a);
    bfma8(v3, __int_as_float(r3.x) * dinv[r3.y], b);
    i += 4;
  }
  if (i + 2 <= end) {
    int2 r0 = recs[i];     int2 r1 = recs[i + 1];
    uint4 v0 = *reinterpret_cast<const uint4*>(&h[(size_t)r0.y * HID + p8]);
    uint4 v1 = *reinterpret_cast<const uint4*>(&h[(size_t)r1.y * HID + p8]);
    bfma8(v0, __int_as_float(r0.x) * dinv[r0.y], a);
    bfma8(v1, __int_as_float(r1.x) * dinv[r1.y], b);
    i += 2;
  }
  if (i < end) {
    int2 r0 = recs[i];
    uint4 v0 = *reinterpret_cast<const uint4*>(&h[(size_t)r0.y * HID + p8]);
    bfma8(v0, __int_as_float(r0.x) * dinv[r0.y], a);
  }
#pragma unroll
  for (int j = 0; j < 8; ++j) r[j] = (a[j] + b[j]) * di;   // apply dinv[dst] once
}

// ============ K3: fused agg1 + gemm2 ============
// 512 threads, 64 nodes/block. Phase A: 8 waves aggregate h1 = relu(conv1+b1);
// each lane writes its 8 feats to h1 (global fp32 resid) AND the gemm X-tile in
// LDS. Phase B: 64x64 gemm h2 = h1@W2^T straight from LDS (no restage, no reread).
// h2 is a separate buffer: writing h in-place would race other blocks' gathers.

__global__ __launch_bounds__(512) void k_agg_gemm(const u16* __restrict__ h,
                                                  const int2* __restrict__ recs,
                                                  const int* __restrict__ offs,
                                                  const int* __restrict__ cnt,
                                                  const float* __restrict__ dinv,
                                                  const float* __restrict__ bias,
                                                  const float* __restrict__ W2,
                                                  float* __restrict__ h1,
                                                  u16* __restrict__ h2,
                                                  int n_nodes) {
  __shared__ float S[2 * 64 * PAD];
  float* XT = S;
  float* WL = S + 64 * PAD;
  int tid = threadIdx.x;
  int lane = tid & 63;
  int p8 = (lane & 7) * 8;
  int nl = (tid >> 6) * 8 + (lane >> 3);        // 0..63 local node
  int node = blockIdx.x * 64 + nl;
  if (node < n_nodes) {
    float di = dinv[node];
    float r[8];
    agg_node(h, recs, dinv, offs[node], offs[node] + cnt[node], node, di,
             lane, p8, r);
    float4 bb0 = *reinterpret_cast<const float4*>(&bias[p8]);
    float4 bb1 = *reinterpret_cast<const float4*>(&bias[p8 + 4]);
    r[0] += bb0.x; r[1] += bb0.y; r[2] += bb0.z; r[3] += bb0.w;
    r[4] += bb1.x; r[5] += bb1.y; r[6] += bb1.z; r[7] += bb1.w;
#pragma unroll
    for (int j = 0; j < 8; ++j) r[j] = fmaxf(r[j], 0.f);
    float4 lo = make_float4(r[0], r[1], r[2], r[3]);
    float4 hi = make_float4(r[4], r[5], r[6], r[7]);
    *reinterpret_cast<float4*>(&h1[(size_t)node * HID + p8]) = lo;
    *reinterpret_cast<float4*>(&h1[(size_t)node * HID + p8 + 4]) = hi;
    *reinterpret_cast<float4*>(&XT[nl * PAD + p8]) = lo;
    *reinterpret_cast<float4*>(&XT[nl * PAD + p8 + 4]) = hi;
  }
  // Phase B (all threads; gemm_tile starts with __syncthreads covering XT writes)
  gemm_tile<HID, true>(nullptr, W2, h2, XT, WL, blockIdx.x * 64, n_nodes, tid);
}

// ============ K4: final aggregation (layer 2) ============
// out = di*(sum w*dinv[s]*h2[s] + di*h2[node]) + b2 + h1

__global__ __launch_bounds__(256) void k_agg2(const u16* __restrict__ h,
                                              const int2* __restrict__ recs,
                                              const int* __restrict__ offs,
                                              const int* __restrict__ cnt,
                                              const float* __restrict__ dinv,
                                              const float* __restrict__ bias,
                                              const float* __restrict__ resid,
                                              float* __restrict__ out, int n_nodes) {
  int tid = threadIdx.x;
  int lane = tid & 63;
  int p8 = (lane & 7) * 8;
  int node = (blockIdx.x * 4 + (tid >> 6)) * 8 + (lane >> 3);   // 32 nodes/block
  if (node >= n_nodes) return;
  float di = dinv[node];
  float r[8];
  agg_node(h, recs, dinv, offs[node], offs[node] + cnt[node], node, di,
           lane, p8, r);
  float4 bb0 = *reinterpret_cast<const float4*>(&bias[p8]);
  float4 bb1 = *reinterpret_cast<const float4*>(&bias[p8 + 4]);
  float4 rs0 = *reinterpret_cast<const float4*>(&resid[(size_t)node * HID + p8]);
  float4 rs1 = *reinterpret_cast<const float4*>(&resid[(size_t)node * HID + p8 + 4]);
  r[0] += bb0.x + rs0.x; r[1] += bb0.y + rs0.y;
  r[2] += bb0.z + rs0.z; r[3] += bb0.w + rs0.w;
  r[4] += bb1.x + rs1.x; r[5] += bb1.y + rs1.y;
  r[6] += bb1.z + rs1.z; r[7] += bb1.w + rs1.w;
  *reinterpret_cast<float4*>(&out[(size_t)node * HID + p8]) =
      make_float4(r[0], r[1], r[2], r[3]);
  *reinterpret_cast<float4*>(&out[(size_t)node * HID + p8 + 4]) =
      make_float4(r[4], r[5], r[6], r[7]);
}

// ============ launcher ============

extern "C" void kernel_launch(void* const* d_in, const int* in_sizes, int n_in,
                              void* d_out, int out_size, void* d_ws, size_t ws_size,
                              hipStream_t stream) {
  const float* x  = (const float*)d_in[0];
  const int*   ei = (const int*)d_in[1];
  const float* ew = (const float*)d_in[2];
  const float* W1 = (const float*)d_in[3];
  const float* b1 = (const float*)d_in[4];
  const float* W2 = (const float*)d_in[5];
  const float* b2 = (const float*)d_in[6];
  float* out = (float*)d_out;

  const int N = in_sizes[0] / DIN;
  const int E = in_sizes[2];
  const int* src = ei;        // ei shape (2,E) row-major
  const int* dst = ei + E;

  const int NBC = (N + 255) >> 8;          // coarse buckets (196 for N=50000)
  const int chunk = (E + NBLK - 1) / NBLK;
  const int nslab = NBC << CSH;            // total slab entries

  char* p = (char*)d_ws;
  auto carve = [&](size_t bytes) {
    char* r = p;
    p += (bytes + 255) & ~(size_t)255;
    return r;
  };
  int*   cursor = (int*)carve(256 * 4);
  int*   offs   = (int*)carve((size_t)N * 4);
  int*   cnt    = (int*)carve((size_t)N * 4);
  float* dinv   = (float*)carve((size_t)N * 4);
  int2*  bufA   = (int2*)carve((size_t)nslab * 8);
  int2*  bufB   = (int2*)carve((size_t)nslab * 8);
  u16*   h      = (u16*)carve((size_t)N * HID * 2);   // bf16 gemm1 output
  u16*   h2     = (u16*)carve((size_t)N * HID * 2);   // bf16 gemm2 output
  float* h1     = (float*)carve((size_t)N * HID * 4); // fp32 layer-1 activations

  int gblk = (N + 63) / 64;                   // 64-node tiles (782)
  int ablk = (N + 31) / 32;                   // 32 nodes per 256-thread block

  // ---- K1: build (edges) + gemm1 (independent) in one launch ----
  hipMemsetAsync(cursor, 0, 256 * 4, stream);
  k_build_gemm<<<NBLK + gblk, 512, 0, stream>>>(src, dst, ew, cursor, bufA, E, chunk,
                                                x, W1, h, N);
  // ---- K2: bucket sort -> dst-grouped records + dinv ----
  k_passB<<<NBC, 1024, 0, stream>>>(bufA, cursor, bufB, offs, cnt, dinv, NBC, N);
  // ---- K3: agg1 (+bias,relu) fused with gemm2 ----
  k_agg_gemm<<<gblk, 512, 0, stream>>>(h, bufB, offs, cnt, dinv, b1, W2, h1, h2, N);
  // ---- K4: agg2 + bias + resid -> out ----
  k_agg2<<<ablk, 256, 0, stream>>>(h2, bufB, offs, cnt, dinv, b2, h1, out, N);
}

// Round 7
// 215.881 us; speedup vs baseline: 1.9961x; 1.0010x over previous
//
#include <hip/hip_runtime.h>

#define HID 64
#define DIN 128
#define NBLK 512                // blocks for the build pass
#define CSH 14                  // slab capacity shift: 16384 entries per bucket
#define CAP (1 << CSH)
#define PAD 68                  // float4-aligned LDS row stride

typedef unsigned long long ull;
typedef unsigned short u16;

static __device__ __forceinline__ u16 f2bf(float f) {
  unsigned u = __float_as_uint(f);
  unsigned lsb = (u >> 16) & 1u;
  u += 0x7fffu + lsb;
  return (u16)(u >> 16);
}

// ============ shared gemm tile: 512 threads, 64x64 output, self-transposing W ====
// out[n0+m][j] = sum_d X[n0+m][d] * W[j][d];  m = ty, ty+32; j = 4*tx..4*tx+3.
// W staging lane map: qd = gq>>6 (wave-uniform), j = gq&63 (lane-sweep). The 4
// transpose writes then hit 64 CONSECUTIVE floats of one LDS row each -> 2
// lanes/bank = conflict-free. (Round-6 map j=gq>>4,qd=gq&15 put 16 lanes on 2
// banks: 8-way conflict, 1.65M SQ_LDS_BANK_CONFLICT.) Global W read becomes a
// stride-K gather but W is 32KB L2-hot across all blocks. XT_PRELOADED: XT was
// filled by caller (fused agg epilogue) -> skip X staging.

template <int K, bool XT_PRELOADED>
__device__ __forceinline__ void gemm_tile(const float* __restrict__ X,
                                          const float* __restrict__ W,
                                          u16* __restrict__ out,
                                          float* XT, float* WL,
                                          int n0, int n_nodes, int tid) {
  const int tx = tid & 15;
  const int ty = tid >> 4;                // 0..31
  float acc[2][4] = {{0.f}};

  for (int ph = 0; ph < K / 64; ++ph) {
    const int d0 = ph * 64;
    __syncthreads();
    if (!XT_PRELOADED) {
#pragma unroll
      for (int k = 0; k < 2; ++k) {
        int f = tid + k * 512;            // 1024 float4 slots: 64 rows x 16 quads
        int r = f >> 4, q = f & 15;
        int n = n0 + r;
        float4 xv = (n < n_nodes)
          ? *reinterpret_cast<const float4*>(&X[(size_t)n * K + d0 + 4 * q])
          : make_float4(0.f, 0.f, 0.f, 0.f);
        *reinterpret_cast<float4*>(&XT[r * PAD + 4 * q]) = xv;
      }
    }
#pragma unroll
    for (int k = 0; k < 2; ++k) {
      int gq = tid + k * 512;             // 1024 slots: 16 d-quads x 64 j
      int qd = gq >> 6, j = gq & 63;
      float4 wv = *reinterpret_cast<const float4*>(&W[(size_t)j * K + d0 + 4 * qd]);
      WL[(4 * qd + 0) * PAD + j] = wv.x;
      WL[(4 * qd + 1) * PAD + j] = wv.y;
      WL[(4 * qd + 2) * PAD + j] = wv.z;
      WL[(4 * qd + 3) * PAD + j] = wv.w;
    }
    __syncthreads();
#pragma unroll 4
    for (int dd = 0; dd < 64; dd += 4) {
      float4 ws[4];
#pragma unroll
      for (int dk = 0; dk < 4; ++dk)
        ws[dk] = *reinterpret_cast<const float4*>(&WL[(dd + dk) * PAD + 4 * tx]);
      float4 x0 = *reinterpret_cast<const float4*>(&XT[ty * PAD + dd]);
      float4 x1 = *reinterpret_cast<const float4*>(&XT[(ty + 32) * PAD + dd]);
      float xm0[4] = {x0.x, x0.y, x0.z, x0.w};
      float xm1[4] = {x1.x, x1.y, x1.z, x1.w};
#pragma unroll
      for (int dk = 0; dk < 4; ++dk) {
        acc[0][0] = fmaf(xm0[dk], ws[dk].x, acc[0][0]);
        acc[0][1] = fmaf(xm0[dk], ws[dk].y, acc[0][1]);
        acc[0][2] = fmaf(xm0[dk], ws[dk].z, acc[0][2]);
        acc[0][3] = fmaf(xm0[dk], ws[dk].w, acc[0][3]);
        acc[1][0] = fmaf(xm1[dk], ws[dk].x, acc[1][0]);
        acc[1][1] = fmaf(xm1[dk], ws[dk].y, acc[1][1]);
        acc[1][2] = fmaf(xm1[dk], ws[dk].z, acc[1][2]);
        acc[1][3] = fmaf(xm1[dk], ws[dk].w, acc[1][3]);
      }
    }
  }

#pragma unroll
  for (int mi = 0; mi < 2; ++mi) {
    int n = n0 + mi * 32 + ty;
    if (n < n_nodes) {
      ushort4 o = make_ushort4(f2bf(acc[mi][0]), f2bf(acc[mi][1]),
                               f2bf(acc[mi][2]), f2bf(acc[mi][3]));
      *reinterpret_cast<ushort4*>(&out[(size_t)n * HID + 4 * tx]) = o;
    }
  }
}

// ============ K1: fused build + layer-1 GEMM (independent block roles) ============
// b < NBLK: edge build (LDS hist + slab reservation + scatter; per-edge atomics
// LDS-only — round-3 lesson: per-edge GLOBAL atomics = 100MB writeback, never).
// Edge loads are int4/float4: 4 edges/thread/iter (build is issue-bound, not BW).
// b >= NBLK: 64x64 gemm1 tile h = x@W1^T (bf16, dinv NOT baked — not ready yet).

__global__ __launch_bounds__(512) void k_build_gemm(const int* __restrict__ src,
                                                    const int* __restrict__ dst,
                                                    const float* __restrict__ ew,
                                                    int* __restrict__ cursor,
                                                    int2* __restrict__ bufA,
                                                    int E, int chunk,
                                                    const float* __restrict__ x,
                                                    const float* __restrict__ W1,
                                                    u16* __restrict__ h,
                                                    int n_nodes) {
  __shared__ float S[2 * 64 * PAD];
  int b = blockIdx.x, tid = threadIdx.x;
  if (b >= NBLK) {               // gemm1 tile blocks
    gemm_tile<DIN, false>(x, W1, h, S, S + 64 * PAD, (b - NBLK) * 64, n_nodes, tid);
    return;
  }
  int* hst = (int*)S;
  int* cur = (int*)S + 256;
  if (tid < 256) hst[tid] = 0;
  __syncthreads();
  int e0 = b * chunk, e1 = min(E, e0 + chunk);   // chunk % 4 == 0, e0 16B-aligned
  int nfull = (e1 - e0) & ~3;
  int rtail = (e1 - e0) - nfull;
  // pass 1: LDS histogram, 4 edges per int4
  for (int e = e0 + 4 * tid; e < e0 + nfull; e += 4 * 512) {
    int4 d4 = *reinterpret_cast<const int4*>(&dst[e]);
    atomicAdd(&hst[d4.x >> 8], 1);
    atomicAdd(&hst[d4.y >> 8], 1);
    atomicAdd(&hst[d4.z >> 8], 1);
    atomicAdd(&hst[d4.w >> 8], 1);
  }
  if (tid < rtail) atomicAdd(&hst[dst[e0 + nfull + tid] >> 8], 1);
  __syncthreads();
  // reserve a contiguous run in each bucket's slab
  if (tid < 256) {
    int c = hst[tid];
    int ofs = (c > 0) ? atomicAdd(&cursor[tid], c) : 0;
    cur[tid] = (tid << CSH) + ofs;
  }
  __syncthreads();
  // pass 2: scatter records, 4 edges per iteration
  for (int e = e0 + 4 * tid; e < e0 + nfull; e += 4 * 512) {
    int4 s4 = *reinterpret_cast<const int4*>(&src[e]);
    int4 d4 = *reinterpret_cast<const int4*>(&dst[e]);
    float4 w4 = *reinterpret_cast<const float4*>(&ew[e]);
    int p0 = atomicAdd(&cur[d4.x >> 8], 1);
    bufA[p0] = make_int2(__float_as_int(w4.x), (int)(((unsigned)s4.x << 16) | (unsigned)d4.x));
    int p1 = atomicAdd(&cur[d4.y >> 8], 1);
    bufA[p1] = make_int2(__float_as_int(w4.y), (int)(((unsigned)s4.y << 16) | (unsigned)d4.y));
    int p2 = atomicAdd(&cur[d4.z >> 8], 1);
    bufA[p2] = make_int2(__float_as_int(w4.z), (int)(((unsigned)s4.z << 16) | (unsigned)d4.z));
    int p3 = atomicAdd(&cur[d4.w >> 8], 1);
    bufA[p3] = make_int2(__float_as_int(w4.w), (int)(((unsigned)s4.w << 16) | (unsigned)d4.w));
  }
  if (tid < rtail) {
    int e = e0 + nfull + tid;
    int s = src[e], d = dst[e];
    int p = atomicAdd(&cur[d >> 8], 1);
    bufA[p] = make_int2(__float_as_int(ew[e]), (int)(((unsigned)s << 16) | (unsigned)d));
  }
}

// ============ K2: one block per coarse bucket -> dst-grouped + offs/cnt + dinv ============
// 1024 threads/block (grid pinned at NBC=196 -> latency-bound, maximize waves).
// Records cached in registers across the two phases: bufA read ONCE.
// Output record = (w_bits, src); norm factored (w*dinv[src] in agg, *dinv[dst] once).

__global__ __launch_bounds__(1024) void k_passB(const int2* __restrict__ bufA,
                                                const int* __restrict__ cursor,
                                                int2* __restrict__ bufB,
                                                int* __restrict__ offs,
                                                int* __restrict__ cnt,
                                                float* __restrict__ dinv,
                                                int NBC, int N) {
  int bin = blockIdx.x, tid = threadIdx.x;
  __shared__ int h2[256];
  __shared__ int cur[256];
  __shared__ float dg[256];
  int bbase = bin << CSH;
  int m = cursor[bin];
  if (tid < 256) { h2[tid] = 0; dg[tid] = 0.f; }
  __syncthreads();
  // phase 1: fine histogram of dst&255, records cached in registers
  int2 rloc[16];                 // CAP/1024 = 16 max records per thread
#pragma unroll
  for (int k = 0; k < 16; ++k) {
    int i = tid + k * 1024;
    if (i < m) {
      rloc[k] = bufA[bbase + i];
      atomicAdd(&h2[(unsigned)rloc[k].y & 255u], 1);
    }
  }
  __syncthreads();
  int own = (tid < 256) ? h2[tid] : 0;
  // inclusive Hillis-Steele scan over 256 bins
  for (int o = 1; o < 256; o <<= 1) {
    int u = 0;
    if (tid < 256 && tid >= o) u = h2[tid - o];
    __syncthreads();
    if (tid < 256) h2[tid] += u;
    __syncthreads();
  }
  int nd = (bin << 8) + tid;
  if (tid < 256) {
    int excl = h2[tid] - own;
    cur[tid] = excl;
    if (nd < N) { offs[nd] = bbase + excl; cnt[nd] = own; }
  }
  __syncthreads();
  // phase 2: scatter into dst-grouped order as (w, src) + weighted degree
#pragma unroll
  for (int k = 0; k < 16; ++k) {
    int i = tid + k * 1024;
    if (i < m) {
      int2 r = rloc[k];
      unsigned sd = (unsigned)r.y;
      int dl = (int)(sd & 255u);
      int p = atomicAdd(&cur[dl], 1);
      bufB[bbase + p] = make_int2(r.x, (int)(sd >> 16));
      atomicAdd(&dg[dl], __int_as_float(r.x));
    }
  }
  __syncthreads();
  if (tid < 256 && nd < N) dinv[nd] = rsqrtf(1.0f + dg[tid]);  // self-loop w=1; deg>=1
}

// ============ agg core: 8-lane group per node, shfl-shared records ============
// Per 8 edges: one 64B record wave-load; lane pre-multiplies w*dinv[src] (1 L2-hot
// gather), 64-bit shfl redistributes. a/b dual accumulators for FMA ILP.

__device__ __forceinline__ void bfma8(const uint4& v, float w, float* a) {
  a[0] = fmaf(__uint_as_float(v.x << 16), w, a[0]);
  a[1] = fmaf(__uint_as_float(v.x & 0xffff0000u), w, a[1]);
  a[2] = fmaf(__uint_as_float(v.y << 16), w, a[2]);
  a[3] = fmaf(__uint_as_float(v.y & 0xffff0000u), w, a[3]);
  a[4] = fmaf(__uint_as_float(v.z << 16), w, a[4]);
  a[5] = fmaf(__uint_as_float(v.z & 0xffff0000u), w, a[5]);
  a[6] = fmaf(__uint_as_float(v.w << 16), w, a[6]);
  a[7] = fmaf(__uint_as_float(v.w & 0xffff0000u), w, a[7]);
}

// accumulates di*(sum_e w*dinv[s]*h[s] + di*h[node]) into r[8] (pre-bias)
__device__ __forceinline__ void agg_node(const u16* __restrict__ h,
                                         const int2* __restrict__ recs,
                                         const float* __restrict__ dinv,
                                         int beg, int end, int node, float di,
                                         int lane, int p8, float* r) {
  float a[8], b[8];
  {
    uint4 v = *reinterpret_cast<const uint4*>(&h[(size_t)node * HID + p8]);
    a[0] = __uint_as_float(v.x << 16) * di;          // self: di*(di*h) after epilogue
    a[1] = __uint_as_float(v.x & 0xffff0000u) * di;
    a[2] = __uint_as_float(v.y << 16) * di;
    a[3] = __uint_as_float(v.y & 0xffff0000u) * di;
    a[4] = __uint_as_float(v.z << 16) * di;
    a[5] = __uint_as_float(v.z & 0xffff0000u) * di;
    a[6] = __uint_as_float(v.w << 16) * di;
    a[7] = __uint_as_float(v.w & 0xffff0000u) * di;
#pragma unroll
    for (int j = 0; j < 8; ++j) b[j] = 0.f;
  }

  const int gb = lane & 56;           // group base lane
  int i = beg;
  while (i + 8 <= end) {              // 8 edges per iteration, 1 record wave-load
    ull rr = *reinterpret_cast<const ull*>(&recs[i + (lane & 7)]);
    float wd = __uint_as_float((unsigned)rr) * dinv[(int)(rr >> 32)];
    rr = (rr & 0xffffffff00000000ull) | (ull)__float_as_uint(wd);
#pragma unroll
    for (int k = 0; k < 8; ++k) {
      ull q = __shfl(rr, gb | k, 64);
      float wk = __uint_as_float((unsigned)q);
      int sk = (int)(q >> 32);
      uint4 vk = *reinterpret_cast<const uint4*>(&h[(size_t)sk * HID + p8]);
      bfma8(vk, wk, (k & 1) ? b : a);
    }
    i += 8;
  }
  if (i + 4 <= end) {
    int2 r0 = recs[i];     int2 r1 = recs[i + 1];
    int2 r2 = recs[i + 2]; int2 r3 = recs[i + 3];
    uint4 v0 = *reinterpret_cast<const uint4*>(&h[(size_t)r0.y * HID + p8]);
    uint4 v1 = *reinterpret_cast<const uint4*>(&h[(size_t)r1.y * HID + p8]);
    uint4 v2 = *reinterpret_cast<const uint4*>(&h[(size_t)r2.y * HID + p8]);
    uint4 v3 = *reinterpret_cast<const uint4*>(&h[(size_t)r3.y * HID + p8]);
    bfma8(v0, __int_as_float(r0.x) * dinv[r0.y], a);
    bfma8(v1, __int_as_float(r1.x) * dinv[r1.y], b);
    bfma8(v2, __int_as_float(r2.x) * dinv[r2.y], a);
    bfma8(v3, __int_as_float(r3.x) * dinv[r3.y], b);
    i += 4;
  }
  if (i + 2 <= end) {
    int2 r0 = recs[i];     int2 r1 = recs[i + 1];
    uint4 v0 = *reinterpret_cast<const uint4*>(&h[(size_t)r0.y * HID + p8]);
    uint4 v1 = *reinterpret_cast<const uint4*>(&h[(size_t)r1.y * HID + p8]);
    bfma8(v0, __int_as_float(r0.x) * dinv[r0.y], a);
    bfma8(v1, __int_as_float(r1.x) * dinv[r1.y], b);
    i += 2;
  }
  if (i < end) {
    int2 r0 = recs[i];
    uint4 v0 = *reinterpret_cast<const uint4*>(&h[(size_t)r0.y * HID + p8]);
    bfma8(v0, __int_as_float(r0.x) * dinv[r0.y], a);
  }
#pragma unroll
  for (int j = 0; j < 8; ++j) r[j] = (a[j] + b[j]) * di;   // apply dinv[dst] once
}

// ============ K3: fused agg1 + gemm2 ============
// 512 threads, 64 nodes/block. Phase A: 8 waves aggregate h1 = relu(conv1+b1);
// each lane writes its 8 feats to h1 (global fp32 resid) AND the gemm X-tile in
// LDS. Phase B: 64x64 gemm h2 = h1@W2^T straight from LDS (no restage, no reread).
// h2 is a separate buffer: writing h in-place would race other blocks' gathers.

__global__ __launch_bounds__(512) void k_agg_gemm(const u16* __restrict__ h,
                                                  const int2* __restrict__ recs,
                                                  const int* __restrict__ offs,
                                                  const int* __restrict__ cnt,
                                                  const float* __restrict__ dinv,
                                                  const float* __restrict__ bias,
                                                  const float* __restrict__ W2,
                                                  float* __restrict__ h1,
                                                  u16* __restrict__ h2,
                                                  int n_nodes) {
  __shared__ float S[2 * 64 * PAD];
  float* XT = S;
  float* WL = S + 64 * PAD;
  int tid = threadIdx.x;
  int lane = tid & 63;
  int p8 = (lane & 7) * 8;
  int nl = (tid >> 6) * 8 + (lane >> 3);        // 0..63 local node
  int node = blockIdx.x * 64 + nl;
  if (node < n_nodes) {
    float di = dinv[node];
    float r[8];
    agg_node(h, recs, dinv, offs[node], offs[node] + cnt[node], node, di,
             lane, p8, r);
    float4 bb0 = *reinterpret_cast<const float4*>(&bias[p8]);
    float4 bb1 = *reinterpret_cast<const float4*>(&bias[p8 + 4]);
    r[0] += bb0.x; r[1] += bb0.y; r[2] += bb0.z; r[3] += bb0.w;
    r[4] += bb1.x; r[5] += bb1.y; r[6] += bb1.z; r[7] += bb1.w;
#pragma unroll
    for (int j = 0; j < 8; ++j) r[j] = fmaxf(r[j], 0.f);
    float4 lo = make_float4(r[0], r[1], r[2], r[3]);
    float4 hi = make_float4(r[4], r[5], r[6], r[7]);
    *reinterpret_cast<float4*>(&h1[(size_t)node * HID + p8]) = lo;
    *reinterpret_cast<float4*>(&h1[(size_t)node * HID + p8 + 4]) = hi;
    *reinterpret_cast<float4*>(&XT[nl * PAD + p8]) = lo;
    *reinterpret_cast<float4*>(&XT[nl * PAD + p8 + 4]) = hi;
  }
  // Phase B (all threads; gemm_tile starts with __syncthreads covering XT writes)
  gemm_tile<HID, true>(nullptr, W2, h2, XT, WL, blockIdx.x * 64, n_nodes, tid);
}

// ============ K4: final aggregation (layer 2) ============
// out = di*(sum w*dinv[s]*h2[s] + di*h2[node]) + b2 + h1

__global__ __launch_bounds__(256) void k_agg2(const u16* __restrict__ h,
                                              const int2* __restrict__ recs,
                                              const int* __restrict__ offs,
                                              const int* __restrict__ cnt,
                                              const float* __restrict__ dinv,
                                              const float* __restrict__ bias,
                                              const float* __restrict__ resid,
                                              float* __restrict__ out, int n_nodes) {
  int tid = threadIdx.x;
  int lane = tid & 63;
  int p8 = (lane & 7) * 8;
  int node = (blockIdx.x * 4 + (tid >> 6)) * 8 + (lane >> 3);   // 32 nodes/block
  if (node >= n_nodes) return;
  float di = dinv[node];
  float r[8];
  agg_node(h, recs, dinv, offs[node], offs[node] + cnt[node], node, di,
           lane, p8, r);
  float4 bb0 = *reinterpret_cast<const float4*>(&bias[p8]);
  float4 bb1 = *reinterpret_cast<const float4*>(&bias[p8 + 4]);
  float4 rs0 = *reinterpret_cast<const float4*>(&resid[(size_t)node * HID + p8]);
  float4 rs1 = *reinterpret_cast<const float4*>(&resid[(size_t)node * HID + p8 + 4]);
  r[0] += bb0.x + rs0.x; r[1] += bb0.y + rs0.y;
  r[2] += bb0.z + rs0.z; r[3] += bb0.w + rs0.w;
  r[4] += bb1.x + rs1.x; r[5] += bb1.y + rs1.y;
  r[6] += bb1.z + rs1.z; r[7] += bb1.w + rs1.w;
  *reinterpret_cast<float4*>(&out[(size_t)node * HID + p8]) =
      make_float4(r[0], r[1], r[2], r[3]);
  *reinterpret_cast<float4*>(&out[(size_t)node * HID + p8 + 4]) =
      make_float4(r[4], r[5], r[6], r[7]);
}

// ============ launcher ============

extern "C" void kernel_launch(void* const* d_in, const int* in_sizes, int n_in,
                              void* d_out, int out_size, void* d_ws, size_t ws_size,
                              hipStream_t stream) {
  const float* x  = (const float*)d_in[0];
  const int*   ei = (const int*)d_in[1];
  const float* ew = (const float*)d_in[2];
  const float* W1 = (const float*)d_in[3];
  const float* b1 = (const float*)d_in[4];
  const float* W2 = (const float*)d_in[5];
  const float* b2 = (const float*)d_in[6];
  float* out = (float*)d_out;

  const int N = in_sizes[0] / DIN;
  const int E = in_sizes[2];
  const int* src = ei;        // ei shape (2,E) row-major
  const int* dst = ei + E;

  const int NBC = (N + 255) >> 8;          // coarse buckets (196 for N=50000)
  const int chunk = (((E + NBLK - 1) / NBLK) + 3) & ~3;   // multiple of 4 -> int4 loads
  const int nslab = NBC << CSH;            // total slab entries

  char* p = (char*)d_ws;
  auto carve = [&](size_t bytes) {
    char* r = p;
    p += (bytes + 255) & ~(size_t)255;
    return r;
  };
  int*   cursor = (int*)carve(256 * 4);
  int*   offs   = (int*)carve((size_t)N * 4);
  int*   cnt    = (int*)carve((size_t)N * 4);
  float* dinv   = (float*)carve((size_t)N * 4);
  int2*  bufA   = (int2*)carve((size_t)nslab * 8);
  int2*  bufB   = (int2*)carve((size_t)nslab * 8);
  u16*   h      = (u16*)carve((size_t)N * HID * 2);   // bf16 gemm1 output
  u16*   h2     = (u16*)carve((size_t)N * HID * 2);   // bf16 gemm2 output
  float* h1     = (float*)carve((size_t)N * HID * 4); // fp32 layer-1 activations

  int gblk = (N + 63) / 64;                   // 64-node tiles (782)
  int ablk = (N + 31) / 32;                   // 32 nodes per 256-thread block

  // ---- K1: build (edges) + gemm1 (independent) in one launch ----
  hipMemsetAsync(cursor, 0, 256 * 4, stream);
  k_build_gemm<<<NBLK + gblk, 512, 0, stream>>>(src, dst, ew, cursor, bufA, E, chunk,
                                                x, W1, h, N);
  // ---- K2: bucket sort -> dst-grouped records + dinv ----
  k_passB<<<NBC, 1024, 0, stream>>>(bufA, cursor, bufB, offs, cnt, dinv, NBC, N);
  // ---- K3: agg1 (+bias,relu) fused with gemm2 ----
  k_agg_gemm<<<gblk, 512, 0, stream>>>(h, bufB, offs, cnt, dinv, b1, W2, h1, h2, N);
  // ---- K4: agg2 + bias + resid -> out ----
  k_agg2<<<ablk, 256, 0, stream>>>(h2, bufB, offs, cnt, dinv, b2, h1, out, N);
}

// Round 8
// 209.471 us; speedup vs baseline: 2.0571x; 1.0306x over previous
//
#include <hip/hip_runtime.h>

#define HID 64
#define DIN 128
#define NBLK 512                // blocks for the build pass
#define CSH 14                  // slab capacity shift: 16384 entries per bucket
#define CAP (1 << CSH)
#define PAD 68                  // float4-aligned LDS row stride

typedef unsigned long long ull;
typedef unsigned short u16;

static __device__ __forceinline__ u16 f2bf(float f) {
  unsigned u = __float_as_uint(f);
  unsigned lsb = (u >> 16) & 1u;
  u += 0x7fffu + lsb;
  return (u16)(u >> 16);
}

// ============ shared gemm tile: NT threads, (NT/8)x64 output, self-transposing W ====
// out[n0+m][j] = sum_d X[n0+m][d] * W[j][d];  m = ty, ty+NT/16; j = 4*tx..4*tx+3.
// W staging lane map: qd wave-uniform, j lane-sweep -> each transpose write hits 64
// consecutive floats of one LDS row = 2 lanes/bank, conflict-free (round-7 fix:
// 1.65M -> 100K SQ_LDS_BANK_CONFLICT). XT_PRELOADED: XT filled by caller.

template <int K, int NT, bool XT_PRELOADED>
__device__ __forceinline__ void gemm_tile(const float* __restrict__ X,
                                          const float* __restrict__ W,
                                          u16* __restrict__ out,
                                          float* XT, float* WL,
                                          int n0, int n_nodes, int tid) {
  constexpr int ROWS = NT / 8;            // 64 (NT=512) or 32 (NT=256)
  const int tx = tid & 15;
  const int ty = tid >> 4;                // 0..NT/16-1
  float acc[2][4] = {{0.f}};

  for (int ph = 0; ph < K / 64; ++ph) {
    const int d0 = ph * 64;
    __syncthreads();
    if (!XT_PRELOADED) {
#pragma unroll
      for (int k = 0; k < 2; ++k) {       // ROWS*16 slots = NT*2
        int f = tid + k * NT;
        int r = f >> 4, q = f & 15;
        int n = n0 + r;
        float4 xv = (n < n_nodes)
          ? *reinterpret_cast<const float4*>(&X[(size_t)n * K + d0 + 4 * q])
          : make_float4(0.f, 0.f, 0.f, 0.f);
        *reinterpret_cast<float4*>(&XT[r * PAD + 4 * q]) = xv;
      }
    }
#pragma unroll
    for (int k = 0; k < 1024 / NT; ++k) { // 1024 slots: 16 d-quads x 64 j
      int gq = tid + k * NT;
      int qd = gq >> 6, j = gq & 63;
      float4 wv = *reinterpret_cast<const float4*>(&W[(size_t)j * K + d0 + 4 * qd]);
      WL[(4 * qd + 0) * PAD + j] = wv.x;
      WL[(4 * qd + 1) * PAD + j] = wv.y;
      WL[(4 * qd + 2) * PAD + j] = wv.z;
      WL[(4 * qd + 3) * PAD + j] = wv.w;
    }
    __syncthreads();
#pragma unroll 4
    for (int dd = 0; dd < 64; dd += 4) {
      float4 ws[4];
#pragma unroll
      for (int dk = 0; dk < 4; ++dk)
        ws[dk] = *reinterpret_cast<const float4*>(&WL[(dd + dk) * PAD + 4 * tx]);
      float4 x0 = *reinterpret_cast<const float4*>(&XT[ty * PAD + dd]);
      float4 x1 = *reinterpret_cast<const float4*>(&XT[(ty + ROWS / 2) * PAD + dd]);
      float xm0[4] = {x0.x, x0.y, x0.z, x0.w};
      float xm1[4] = {x1.x, x1.y, x1.z, x1.w};
#pragma unroll
      for (int dk = 0; dk < 4; ++dk) {
        acc[0][0] = fmaf(xm0[dk], ws[dk].x, acc[0][0]);
        acc[0][1] = fmaf(xm0[dk], ws[dk].y, acc[0][1]);
        acc[0][2] = fmaf(xm0[dk], ws[dk].z, acc[0][2]);
        acc[0][3] = fmaf(xm0[dk], ws[dk].w, acc[0][3]);
        acc[1][0] = fmaf(xm1[dk], ws[dk].x, acc[1][0]);
        acc[1][1] = fmaf(xm1[dk], ws[dk].y, acc[1][1]);
        acc[1][2] = fmaf(xm1[dk], ws[dk].z, acc[1][2]);
        acc[1][3] = fmaf(xm1[dk], ws[dk].w, acc[1][3]);
      }
    }
  }

#pragma unroll
  for (int mi = 0; mi < 2; ++mi) {
    int n = n0 + mi * (ROWS / 2) + ty;
    if (n < n_nodes) {
      ushort4 o = make_ushort4(f2bf(acc[mi][0]), f2bf(acc[mi][1]),
                               f2bf(acc[mi][2]), f2bf(acc[mi][3]));
      *reinterpret_cast<ushort4*>(&out[(size_t)n * HID + 4 * tx]) = o;
    }
  }
}

// ============ K1: fused build + layer-1 GEMM (independent block roles) ============
// b < NBLK: edge build (LDS hist + slab reservation + scatter; per-edge atomics
// LDS-only — round-3 lesson: per-edge GLOBAL atomics = 100MB writeback, never).
// Edge loads int4/float4: 4 edges/thread/iter. b >= NBLK: 64x64 gemm1 tile.

__global__ __launch_bounds__(512) void k_build_gemm(const int* __restrict__ src,
                                                    const int* __restrict__ dst,
                                                    const float* __restrict__ ew,
                                                    int* __restrict__ cursor,
                                                    int2* __restrict__ bufA,
                                                    int E, int chunk,
                                                    const float* __restrict__ x,
                                                    const float* __restrict__ W1,
                                                    u16* __restrict__ h,
                                                    int n_nodes) {
  __shared__ float S[2 * 64 * PAD];
  int b = blockIdx.x, tid = threadIdx.x;
  if (b >= NBLK) {               // gemm1 tile blocks
    gemm_tile<DIN, 512, false>(x, W1, h, S, S + 64 * PAD, (b - NBLK) * 64, n_nodes, tid);
    return;
  }
  int* hst = (int*)S;
  int* cur = (int*)S + 256;
  if (tid < 256) hst[tid] = 0;
  __syncthreads();
  int e0 = b * chunk, e1 = min(E, e0 + chunk);   // chunk % 4 == 0, e0 16B-aligned
  int nfull = (e1 - e0) & ~3;
  int rtail = (e1 - e0) - nfull;
  // pass 1: LDS histogram, 4 edges per int4
  for (int e = e0 + 4 * tid; e < e0 + nfull; e += 4 * 512) {
    int4 d4 = *reinterpret_cast<const int4*>(&dst[e]);
    atomicAdd(&hst[d4.x >> 8], 1);
    atomicAdd(&hst[d4.y >> 8], 1);
    atomicAdd(&hst[d4.z >> 8], 1);
    atomicAdd(&hst[d4.w >> 8], 1);
  }
  if (tid < rtail) atomicAdd(&hst[dst[e0 + nfull + tid] >> 8], 1);
  __syncthreads();
  // reserve a contiguous run in each bucket's slab
  if (tid < 256) {
    int c = hst[tid];
    int ofs = (c > 0) ? atomicAdd(&cursor[tid], c) : 0;
    cur[tid] = (tid << CSH) + ofs;
  }
  __syncthreads();
  // pass 2: scatter records, 4 edges per iteration
  for (int e = e0 + 4 * tid; e < e0 + nfull; e += 4 * 512) {
    int4 s4 = *reinterpret_cast<const int4*>(&src[e]);
    int4 d4 = *reinterpret_cast<const int4*>(&dst[e]);
    float4 w4 = *reinterpret_cast<const float4*>(&ew[e]);
    int p0 = atomicAdd(&cur[d4.x >> 8], 1);
    bufA[p0] = make_int2(__float_as_int(w4.x), (int)(((unsigned)s4.x << 16) | (unsigned)d4.x));
    int p1 = atomicAdd(&cur[d4.y >> 8], 1);
    bufA[p1] = make_int2(__float_as_int(w4.y), (int)(((unsigned)s4.y << 16) | (unsigned)d4.y));
    int p2 = atomicAdd(&cur[d4.z >> 8], 1);
    bufA[p2] = make_int2(__float_as_int(w4.z), (int)(((unsigned)s4.z << 16) | (unsigned)d4.z));
    int p3 = atomicAdd(&cur[d4.w >> 8], 1);
    bufA[p3] = make_int2(__float_as_int(w4.w), (int)(((unsigned)s4.w << 16) | (unsigned)d4.w));
  }
  if (tid < rtail) {
    int e = e0 + nfull + tid;
    int s = src[e], d = dst[e];
    int p = atomicAdd(&cur[d >> 8], 1);
    bufA[p] = make_int2(__float_as_int(ew[e]), (int)(((unsigned)s << 16) | (unsigned)d));
  }
}

// ============ K2: one block per coarse bucket -> dst-grouped + offs/cnt + dinv ============
// 1024 threads/block (grid pinned at NBC=196 -> latency-bound, maximize waves).
// Records cached in registers across the two phases: bufA read ONCE.
// Output record = (w_bits, src); norm factored (w*dinv[src] in agg, *dinv[dst] once).

__global__ __launch_bounds__(1024) void k_passB(const int2* __restrict__ bufA,
                                                const int* __restrict__ cursor,
                                                int2* __restrict__ bufB,
                                                int* __restrict__ offs,
                                                int* __restrict__ cnt,
                                                float* __restrict__ dinv,
                                                int NBC, int N) {
  int bin = blockIdx.x, tid = threadIdx.x;
  __shared__ int h2[256];
  __shared__ int cur[256];
  __shared__ float dg[256];
  int bbase = bin << CSH;
  int m = cursor[bin];
  if (tid < 256) { h2[tid] = 0; dg[tid] = 0.f; }
  __syncthreads();
  // phase 1: fine histogram of dst&255, records cached in registers
  int2 rloc[16];                 // CAP/1024 = 16 max records per thread
#pragma unroll
  for (int k = 0; k < 16; ++k) {
    int i = tid + k * 1024;
    if (i < m) {
      rloc[k] = bufA[bbase + i];
      atomicAdd(&h2[(unsigned)rloc[k].y & 255u], 1);
    }
  }
  __syncthreads();
  int own = (tid < 256) ? h2[tid] : 0;
  // inclusive Hillis-Steele scan over 256 bins
  for (int o = 1; o < 256; o <<= 1) {
    int u = 0;
    if (tid < 256 && tid >= o) u = h2[tid - o];
    __syncthreads();
    if (tid < 256) h2[tid] += u;
    __syncthreads();
  }
  int nd = (bin << 8) + tid;
  if (tid < 256) {
    int excl = h2[tid] - own;
    cur[tid] = excl;
    if (nd < N) { offs[nd] = bbase + excl; cnt[nd] = own; }
  }
  __syncthreads();
  // phase 2: scatter into dst-grouped order as (w, src) + weighted degree
#pragma unroll
  for (int k = 0; k < 16; ++k) {
    int i = tid + k * 1024;
    if (i < m) {
      int2 r = rloc[k];
      unsigned sd = (unsigned)r.y;
      int dl = (int)(sd & 255u);
      int p = atomicAdd(&cur[dl], 1);
      bufB[bbase + p] = make_int2(r.x, (int)(sd >> 16));
      atomicAdd(&dg[dl], __int_as_float(r.x));
    }
  }
  __syncthreads();
  if (tid < 256 && nd < N) dinv[nd] = rsqrtf(1.0f + dg[tid]);  // self-loop w=1; deg>=1
}

// ============ agg core: 8-lane group per node, shfl-shared records, pipelined ====
// Per 8 edges: one 64B record wave-load + one dinv gather, PREFETCHED one
// iteration ahead so the 2-hop dependent-load chain (recs -> dinv) overlaps the
// previous iteration's 8 h-gathers + FMAs. a/b dual accumulators for FMA ILP.

__device__ __forceinline__ void bfma8(const uint4& v, float w, float* a) {
  a[0] = fmaf(__uint_as_float(v.x << 16), w, a[0]);
  a[1] = fmaf(__uint_as_float(v.x & 0xffff0000u), w, a[1]);
  a[2] = fmaf(__uint_as_float(v.y << 16), w, a[2]);
  a[3] = fmaf(__uint_as_float(v.y & 0xffff0000u), w, a[3]);
  a[4] = fmaf(__uint_as_float(v.z << 16), w, a[4]);
  a[5] = fmaf(__uint_as_float(v.z & 0xffff0000u), w, a[5]);
  a[6] = fmaf(__uint_as_float(v.w << 16), w, a[6]);
  a[7] = fmaf(__uint_as_float(v.w & 0xffff0000u), w, a[7]);
}

// accumulates di*(sum_e w*dinv[s]*h[s] + di*h[node]) into r[8] (pre-bias)
__device__ __forceinline__ void agg_node(const u16* __restrict__ h,
                                         const int2* __restrict__ recs,
                                         const float* __restrict__ dinv,
                                         int beg, int end, int node, float di,
                                         int lane, int p8, float* r) {
  float a[8], b[8];
  {
    uint4 v = *reinterpret_cast<const uint4*>(&h[(size_t)node * HID + p8]);
    a[0] = __uint_as_float(v.x << 16) * di;          // self: di*(di*h) after epilogue
    a[1] = __uint_as_float(v.x & 0xffff0000u) * di;
    a[2] = __uint_as_float(v.y << 16) * di;
    a[3] = __uint_as_float(v.y & 0xffff0000u) * di;
    a[4] = __uint_as_float(v.z << 16) * di;
    a[5] = __uint_as_float(v.z & 0xffff0000u) * di;
    a[6] = __uint_as_float(v.w << 16) * di;
    a[7] = __uint_as_float(v.w & 0xffff0000u) * di;
#pragma unroll
    for (int j = 0; j < 8; ++j) b[j] = 0.f;
  }

  const int gb = lane & 56;           // group base lane
  const int l7 = lane & 7;
  int i = beg;
  if (i + 8 <= end) {
    ull rr = *reinterpret_cast<const ull*>(&recs[i + l7]);
    float dv = dinv[(int)(rr >> 32)];
    for (;;) {
      float wd = __uint_as_float((unsigned)rr) * dv;
      ull ru = (rr & 0xffffffff00000000ull) | (ull)__float_as_uint(wd);
      bool more = (i + 16 <= end);
      ull rr_n = 0; float dv_n = 0.f;
      if (more) {                     // prefetch next iteration's chain
        rr_n = *reinterpret_cast<const ull*>(&recs[i + 8 + l7]);
        dv_n = dinv[(int)(rr_n >> 32)];
      }
#pragma unroll
      for (int k = 0; k < 8; ++k) {
        ull q = __shfl(ru, gb | k, 64);
        float wk = __uint_as_float((unsigned)q);
        int sk = (int)(q >> 32);
        uint4 vk = *reinterpret_cast<const uint4*>(&h[(size_t)sk * HID + p8]);
        bfma8(vk, wk, (k & 1) ? b : a);
      }
      i += 8;
      if (!more) break;
      rr = rr_n; dv = dv_n;
    }
  }
  if (i + 4 <= end) {
    int2 r0 = recs[i];     int2 r1 = recs[i + 1];
    int2 r2 = recs[i + 2]; int2 r3 = recs[i + 3];
    uint4 v0 = *reinterpret_cast<const uint4*>(&h[(size_t)r0.y * HID + p8]);
    uint4 v1 = *reinterpret_cast<const uint4*>(&h[(size_t)r1.y * HID + p8]);
    uint4 v2 = *reinterpret_cast<const uint4*>(&h[(size_t)r2.y * HID + p8]);
    uint4 v3 = *reinterpret_cast<const uint4*>(&h[(size_t)r3.y * HID + p8]);
    bfma8(v0, __int_as_float(r0.x) * dinv[r0.y], a);
    bfma8(v1, __int_as_float(r1.x) * dinv[r1.y], b);
    bfma8(v2, __int_as_float(r2.x) * dinv[r2.y], a);
    bfma8(v3, __int_as_float(r3.x) * dinv[r3.y], b);
    i += 4;
  }
  if (i + 2 <= end) {
    int2 r0 = recs[i];     int2 r1 = recs[i + 1];
    uint4 v0 = *reinterpret_cast<const uint4*>(&h[(size_t)r0.y * HID + p8]);
    uint4 v1 = *reinterpret_cast<const uint4*>(&h[(size_t)r1.y * HID + p8]);
    bfma8(v0, __int_as_float(r0.x) * dinv[r0.y], a);
    bfma8(v1, __int_as_float(r1.x) * dinv[r1.y], b);
    i += 2;
  }
  if (i < end) {
    int2 r0 = recs[i];
    uint4 v0 = *reinterpret_cast<const uint4*>(&h[(size_t)r0.y * HID + p8]);
    bfma8(v0, __int_as_float(r0.x) * dinv[r0.y], a);
  }
#pragma unroll
  for (int j = 0; j < 8; ++j) r[j] = (a[j] + b[j]) * di;   // apply dinv[dst] once
}

// ============ K3: fused agg1 + gemm2 — 256 threads / 32 nodes ============
// Smaller blocks (was 512/64): LDS 26KB -> 6 blocks/CU, grid 1563 (6.1/CU),
// straggler granularity halves, occupancy cap 75% -> 94% (round-7: occ 39%,
// barrier-bound on degree variance). Phase A: 4 waves aggregate h1 =
// relu(conv1+b1) -> h1 (global, resid) + XT (LDS). Phase B: 32x64 gemm2 from LDS.

__global__ __launch_bounds__(256) void k_agg_gemm(const u16* __restrict__ h,
                                                  const int2* __restrict__ recs,
                                                  const int* __restrict__ offs,
                                                  const int* __restrict__ cnt,
                                                  const float* __restrict__ dinv,
                                                  const float* __restrict__ bias,
                                                  const float* __restrict__ W2,
                                                  float* __restrict__ h1,
                                                  u16* __restrict__ h2,
                                                  int n_nodes) {
  __shared__ float S[(32 + 64) * PAD];
  float* XT = S;
  float* WL = S + 32 * PAD;
  int tid = threadIdx.x;
  int lane = tid & 63;
  int p8 = (lane & 7) * 8;
  int nl = (tid >> 6) * 8 + (lane >> 3);        // 0..31 local node
  int node = blockIdx.x * 32 + nl;
  if (node < n_nodes) {
    float di = dinv[node];
    float r[8];
    agg_node(h, recs, dinv, offs[node], offs[node] + cnt[node], node, di,
             lane, p8, r);
    float4 bb0 = *reinterpret_cast<const float4*>(&bias[p8]);
    float4 bb1 = *reinterpret_cast<const float4*>(&bias[p8 + 4]);
    r[0] += bb0.x; r[1] += bb0.y; r[2] += bb0.z; r[3] += bb0.w;
    r[4] += bb1.x; r[5] += bb1.y; r[6] += bb1.z; r[7] += bb1.w;
#pragma unroll
    for (int j = 0; j < 8; ++j) r[j] = fmaxf(r[j], 0.f);
    float4 lo = make_float4(r[0], r[1], r[2], r[3]);
    float4 hi = make_float4(r[4], r[5], r[6], r[7]);
    *reinterpret_cast<float4*>(&h1[(size_t)node * HID + p8]) = lo;
    *reinterpret_cast<float4*>(&h1[(size_t)node * HID + p8 + 4]) = hi;
    *reinterpret_cast<float4*>(&XT[nl * PAD + p8]) = lo;
    *reinterpret_cast<float4*>(&XT[nl * PAD + p8 + 4]) = hi;
  }
  // Phase B (all threads; gemm_tile starts with __syncthreads covering XT writes)
  gemm_tile<HID, 256, true>(nullptr, W2, h2, XT, WL, blockIdx.x * 32, n_nodes, tid);
}

// ============ K4: final aggregation (layer 2) ============
// out = di*(sum w*dinv[s]*h2[s] + di*h2[node]) + b2 + h1

__global__ __launch_bounds__(256) void k_agg2(const u16* __restrict__ h,
                                              const int2* __restrict__ recs,
                                              const int* __restrict__ offs,
                                              const int* __restrict__ cnt,
                                              const float* __restrict__ dinv,
                                              const float* __restrict__ bias,
                                              const float* __restrict__ resid,
                                              float* __restrict__ out, int n_nodes) {
  int tid = threadIdx.x;
  int lane = tid & 63;
  int p8 = (lane & 7) * 8;
  int node = (blockIdx.x * 4 + (tid >> 6)) * 8 + (lane >> 3);   // 32 nodes/block
  if (node >= n_nodes) return;
  float di = dinv[node];
  float r[8];
  agg_node(h, recs, dinv, offs[node], offs[node] + cnt[node], node, di,
           lane, p8, r);
  float4 bb0 = *reinterpret_cast<const float4*>(&bias[p8]);
  float4 bb1 = *reinterpret_cast<const float4*>(&bias[p8 + 4]);
  float4 rs0 = *reinterpret_cast<const float4*>(&resid[(size_t)node * HID + p8]);
  float4 rs1 = *reinterpret_cast<const float4*>(&resid[(size_t)node * HID + p8 + 4]);
  r[0] += bb0.x + rs0.x; r[1] += bb0.y + rs0.y;
  r[2] += bb0.z + rs0.z; r[3] += bb0.w + rs0.w;
  r[4] += bb1.x + rs1.x; r[5] += bb1.y + rs1.y;
  r[6] += bb1.z + rs1.z; r[7] += bb1.w + rs1.w;
  *reinterpret_cast<float4*>(&out[(size_t)node * HID + p8]) =
      make_float4(r[0], r[1], r[2], r[3]);
  *reinterpret_cast<float4*>(&out[(size_t)node * HID + p8 + 4]) =
      make_float4(r[4], r[5], r[6], r[7]);
}

// ============ launcher ============

extern "C" void kernel_launch(void* const* d_in, const int* in_sizes, int n_in,
                              void* d_out, int out_size, void* d_ws, size_t ws_size,
                              hipStream_t stream) {
  const float* x  = (const float*)d_in[0];
  const int*   ei = (const int*)d_in[1];
  const float* ew = (const float*)d_in[2];
  const float* W1 = (const float*)d_in[3];
  const float* b1 = (const float*)d_in[4];
  const float* W2 = (const float*)d_in[5];
  const float* b2 = (const float*)d_in[6];
  float* out = (float*)d_out;

  const int N = in_sizes[0] / DIN;
  const int E = in_sizes[2];
  const int* src = ei;        // ei shape (2,E) row-major
  const int* dst = ei + E;

  const int NBC = (N + 255) >> 8;          // coarse buckets (196 for N=50000)
  const int chunk = (((E + NBLK - 1) / NBLK) + 3) & ~3;   // multiple of 4 -> int4 loads
  const int nslab = NBC << CSH;            // total slab entries

  char* p = (char*)d_ws;
  auto carve = [&](size_t bytes) {
    char* r = p;
    p += (bytes + 255) & ~(size_t)255;
    return r;
  };
  int*   cursor = (int*)carve(256 * 4);
  int*   offs   = (int*)carve((size_t)N * 4);
  int*   cnt    = (int*)carve((size_t)N * 4);
  float* dinv   = (float*)carve((size_t)N * 4);
  int2*  bufA   = (int2*)carve((size_t)nslab * 8);
  int2*  bufB   = (int2*)carve((size_t)nslab * 8);
  u16*   h      = (u16*)carve((size_t)N * HID * 2);   // bf16 gemm1 output
  u16*   h2     = (u16*)carve((size_t)N * HID * 2);   // bf16 gemm2 output
  float* h1     = (float*)carve((size_t)N * HID * 4); // fp32 layer-1 activations

  int gblk  = (N + 63) / 64;                  // 64-node gemm1 tiles (782)
  int gblk2 = (N + 31) / 32;                  // 32-node agg_gemm blocks (1563)
  int ablk  = (N + 31) / 32;                  // 32 nodes per 256-thread block

  // ---- K1: build (edges) + gemm1 (independent) in one launch ----
  hipMemsetAsync(cursor, 0, 256 * 4, stream);
  k_build_gemm<<<NBLK + gblk, 512, 0, stream>>>(src, dst, ew, cursor, bufA, E, chunk,
                                                x, W1, h, N);
  // ---- K2: bucket sort -> dst-grouped records + dinv ----
  k_passB<<<NBC, 1024, 0, stream>>>(bufA, cursor, bufB, offs, cnt, dinv, NBC, N);
  // ---- K3: agg1 (+bias,relu) fused with gemm2 ----
  k_agg_gemm<<<gblk2, 256, 0, stream>>>(h, bufB, offs, cnt, dinv, b1, W2, h1, h2, N);
  // ---- K4: agg2 + bias + resid -> out ----
  k_agg2<<<ablk, 256, 0, stream>>>(h2, bufB, offs, cnt, dinv, b2, h1, out, N);
}